// Round 9
// baseline (1979.696 us; speedup 1.0000x reference)
//
#include <hip/hip_runtime.h>

typedef unsigned short u16;
typedef unsigned int u32;
typedef __bf16 bf16x8 __attribute__((ext_vector_type(8)));
typedef float f32x4 __attribute__((ext_vector_type(4)));

__device__ __forceinline__ float bf2f(u16 h) {
  union { u32 u; float f; } c; c.u = ((u32)h) << 16; return c.f;
}
__device__ __forceinline__ float bflo(u32 u) {
  union { u32 u; float f; } c; c.u = u << 16; return c.f;
}
__device__ __forceinline__ float bfhi(u32 u) {
  union { u32 u; float f; } c; c.u = u & 0xffff0000u; return c.f;
}
// compiler emits packed v_cvt_pk_bf16_f32 for __bf16 casts (RNE)
__device__ __forceinline__ u32 pack2bf(float a, float b) {
  union { __bf16 h[2]; u32 u; } c; c.h[0] = (__bf16)a; c.h[1] = (__bf16)b;
  return c.u;
}
__device__ __forceinline__ u16 f2bf(float f) {
  union { __bf16 h; u16 u; } c; c.h = (__bf16)f; return c.u;
}
__device__ __forceinline__ float relu(float x) { return x > 0.f ? x : 0.f; }

// One-shot conversion of all four weight slices to bf16 [N][Kpad] layouts.
__global__ __launch_bounds__(256) void cvt_all(
    const float* __restrict__ Wi, const float* __restrict__ Wh,
    const float* __restrict__ Wo, u16* __restrict__ dWi, u16* __restrict__ dWh,
    u16* __restrict__ dWo1, u16* __restrict__ dWo2) {
  int i = blockIdx.x * 256 + threadIdx.x;
  if (i < 40960) {
    int n = i / 160, k = i % 160;
    dWi[i] = f2bf(k < 147 ? Wi[n * 147 + k] : 0.f);
  } else if (i < 106496) {
    int j = i - 40960;
    dWh[j] = f2bf(Wh[j]);
  } else if (i < 147456) {
    int j = i - 106496;
    int n = j / 160, k = j % 160;
    dWo1[j] = f2bf(k < 133 ? Wo[n * 389 + k] : 0.f);
  } else {
    int j = i - 147456;
    int n = j / 256, k = j % 256;
    dWo2[j] = f2bf(Wo[n * 389 + 133 + k]);
  }
}

// Persistent 2-phase pipelined GEMM: C[M,256] = A[M,K] * W[256,K]^T.
// BM=32 tiles, double-buffered LDS; grid-stride over tiles; per tile:
//   ISSUE(t+1) [pure global loads -> regs]  ->  COMPUTE(As[cur])  ->
//   WRITE(cur^1) [convert/accum + ds_write (+ amsg store)]  ->  EPI  -> bar.
// T14 issue-early/write-late: next tile's staging loads are in flight under
// the current tile's 64 MFMAs + epilogue.  Single barrier per tile (r3-style
// skeleton: WRITE targets the buffer nobody reads since the last barrier).
// 4 waves, each 32 rows x 64-col band; swapped-operand MFMA (lane holds 4
// consecutive output cols); stores bf16=8B / f32=16B.  Output must not alias
// any input (cross-wave WAR, round-4 lesson).
// ASRC: 0 = A from f32 global [M][Kreal] (KPAD=160, guarded, converted)
//       2 = A row r = bf16( Ab[idx1[r]] - relu(Ab2[idx2[r]]) )  [KPAD=256]
//       3 = A row r = bf16( sum_{j<6} relu(Ab[idx1[r*6+j]]) )   [KPAD=256]
//           (holds 24 uint4 in flight; MINW=2 gives the VGPR headroom)
// EPI:  0 = bf16 acc -> outb0
//       1 = v=acc+bias[c]; bf16 v -> outb0; relu(v) f32 -> outf
//       2 = v=acc+bf2f(addb[idx]); bf16 v -> outb0
//       3 = v=acc+bf2f(addb[idx]); relu(v) f32 -> outf
template <int ASRC, int EPI, int KPAD, int WAMSG, int MINW>
__global__ __launch_bounds__(256, MINW) void gemm8(
    const float* __restrict__ Af, int Kreal,
    const u16* __restrict__ Ab, const u16* __restrict__ Ab2,
    const int* __restrict__ idx1, const int* __restrict__ idx2,
    const u16* __restrict__ Bw,
    const u16* __restrict__ addb, const float* __restrict__ bias,
    u16* __restrict__ outb0, float* __restrict__ outf,
    u16* __restrict__ amsg_out, int ntiles) {
  constexpr int LDK = KPAD + 8;  // row stride 336/528B: banks spread (2-4 way)
  __shared__ u16 As[2][32 * LDK];

  const int tid = threadIdx.x;
  const int lane = tid & 63;
  const int wn = (tid >> 6) * 64;
  const int lm = lane & 15, lg = lane >> 4;
  const int koff = lg * 8;
  const int stride = gridDim.x;
  const int srow = tid >> 3, sseg = tid & 7;  // staging: 8 threads/row, 64B seg

  // staging registers, live across COMPUTE (issue-early / write-late)
  float sf[ASRC == 0 ? 20 : 1];
  uint4 sva[ASRC == 3 ? 24 : (ASRC == 2 ? 4 : 1)];
  uint4 svb[ASRC == 2 ? 4 : 1];

  auto ISSUE = [&](int t) {
    const int m0 = t * 32;
    if constexpr (ASRC == 0) {
      static_assert(ASRC != 0 || KPAD == 160, "ASRC0 map assumes KPAD=160");
#pragma unroll
      for (int p = 0; p < 10; ++p) {  // 32*160/512 pairs per thread
        int e = (p * 256 + tid) * 2;
        int row = e / KPAD, k = e % KPAD;
        const float* src = Af + (size_t)(m0 + row) * Kreal + k;
        sf[2 * p] = (k < Kreal) ? src[0] : 0.f;
        sf[2 * p + 1] = (k + 1 < Kreal) ? src[1] : 0.f;
      }
    } else if constexpr (ASRC == 2) {
      const int gr = m0 + srow;
      const u16* pa = Ab + (size_t)idx1[gr] * 256 + sseg * 32;
      const u16* pb = Ab2 + (size_t)idx2[gr] * 256 + sseg * 32;
#pragma unroll
      for (int i = 0; i < 4; ++i) {
        sva[i] = *reinterpret_cast<const uint4*>(pa + i * 8);
        svb[i] = *reinterpret_cast<const uint4*>(pb + i * 8);
      }
    } else {
      const int gr = m0 + srow;
      const int* nbp = idx1 + gr * 6;
      const u16* base = Ab + sseg * 32;
#pragma unroll
      for (int j = 0; j < 6; ++j) {
        const u16* p = base + (size_t)nbp[j] * 256;
#pragma unroll
        for (int c = 0; c < 4; ++c)
          sva[j * 4 + c] = *reinterpret_cast<const uint4*>(p + c * 8);
      }
    }
  };

  auto WRITE = [&](int buf, int t) {
    u16* dst = As[buf];
    if constexpr (ASRC == 0) {
#pragma unroll
      for (int p = 0; p < 10; ++p) {
        int e = (p * 256 + tid) * 2;
        int row = e / KPAD, k = e % KPAD;
        *reinterpret_cast<u32*>(&dst[row * LDK + k]) =
            pack2bf(sf[2 * p], sf[2 * p + 1]);
      }
    } else if constexpr (ASRC == 2) {
      u16* d = &dst[srow * LDK + sseg * 32];
#pragma unroll
      for (int i = 0; i < 4; ++i) {
        uint4 o;
        o.x = pack2bf(bflo(sva[i].x) - relu(bflo(svb[i].x)),
                      bfhi(sva[i].x) - relu(bfhi(svb[i].x)));
        o.y = pack2bf(bflo(sva[i].y) - relu(bflo(svb[i].y)),
                      bfhi(sva[i].y) - relu(bfhi(svb[i].y)));
        o.z = pack2bf(bflo(sva[i].z) - relu(bflo(svb[i].z)),
                      bfhi(sva[i].z) - relu(bfhi(svb[i].z)));
        o.w = pack2bf(bflo(sva[i].w) - relu(bflo(svb[i].w)),
                      bfhi(sva[i].w) - relu(bfhi(svb[i].w)));
        *reinterpret_cast<uint4*>(d + i * 8) = o;
      }
    } else {
      const int gr = t * 32 + srow;
      u16* d = &dst[srow * LDK + sseg * 32];
#pragma unroll
      for (int c = 0; c < 4; ++c) {
        float s[8];
#pragma unroll
        for (int e = 0; e < 8; ++e) s[e] = 0.f;
#pragma unroll
        for (int j = 0; j < 6; ++j) {
          uint4 v = sva[j * 4 + c];
          s[0] += relu(bflo(v.x)); s[1] += relu(bfhi(v.x));
          s[2] += relu(bflo(v.y)); s[3] += relu(bfhi(v.y));
          s[4] += relu(bflo(v.z)); s[5] += relu(bfhi(v.z));
          s[6] += relu(bflo(v.w)); s[7] += relu(bfhi(v.w));
        }
        uint4 o;
        o.x = pack2bf(s[0], s[1]); o.y = pack2bf(s[2], s[3]);
        o.z = pack2bf(s[4], s[5]); o.w = pack2bf(s[6], s[7]);
        *reinterpret_cast<uint4*>(d + c * 8) = o;
        if constexpr (WAMSG)
          *reinterpret_cast<uint4*>(amsg_out + (size_t)gr * 256 + sseg * 32 + c * 8) = o;
      }
    }
  };

  float4 bb[4];
  if constexpr (EPI == 1) {
#pragma unroll
    for (int j = 0; j < 4; ++j)
      bb[j] = *reinterpret_cast<const float4*>(bias + wn + j * 16 + lg * 4);
  }

  int tile = blockIdx.x;
  ISSUE(tile);
  WRITE(0, tile);
  __syncthreads();
  int cur = 0;

  while (true) {
    const int nxt = tile + stride;
    const bool hn = nxt < ntiles;
    if (hn) ISSUE(nxt);

    f32x4 acc[2][4];
#pragma unroll
    for (int i = 0; i < 2; ++i)
#pragma unroll
      for (int j = 0; j < 4; ++j) acc[i][j] = (f32x4)(0.f);

    const u16* asb = As[cur];
#pragma unroll
    for (int kk = 0; kk < KPAD / 32; ++kk) {
      const int k0 = kk * 32 + koff;
      bf16x8 a0 = *reinterpret_cast<const bf16x8*>(&asb[lm * LDK + k0]);
      bf16x8 a1 = *reinterpret_cast<const bf16x8*>(&asb[(16 + lm) * LDK + k0]);
#pragma unroll
      for (int jw = 0; jw < 4; ++jw) {
        bf16x8 b = *reinterpret_cast<const bf16x8*>(
            Bw + (size_t)(wn + jw * 16 + lm) * KPAD + k0);
        acc[0][jw] = __builtin_amdgcn_mfma_f32_16x16x32_bf16(b, a0, acc[0][jw], 0, 0, 0);
        acc[1][jw] = __builtin_amdgcn_mfma_f32_16x16x32_bf16(b, a1, acc[1][jw], 0, 0, 0);
      }
    }

    if (hn) WRITE(cur ^ 1, nxt);  // ds_writes drain under the epilogue

    const int m0 = tile * 32;
#pragma unroll
    for (int im = 0; im < 2; ++im) {
#pragma unroll
      for (int jw = 0; jw < 4; ++jw) {
        const int r = m0 + im * 16 + lm;
        const int c0 = wn + jw * 16 + lg * 4;
        const size_t idx = (size_t)r * 256 + c0;
        f32x4 v = acc[im][jw];
        if constexpr (EPI == 0) {
          uint2 o; o.x = pack2bf(v[0], v[1]); o.y = pack2bf(v[2], v[3]);
          *reinterpret_cast<uint2*>(outb0 + idx) = o;
        } else if constexpr (EPI == 1) {
          v[0] += bb[jw].x; v[1] += bb[jw].y; v[2] += bb[jw].z; v[3] += bb[jw].w;
          uint2 o; o.x = pack2bf(v[0], v[1]); o.y = pack2bf(v[2], v[3]);
          *reinterpret_cast<uint2*>(outb0 + idx) = o;
          float4 rl = {relu(v[0]), relu(v[1]), relu(v[2]), relu(v[3])};
          *reinterpret_cast<float4*>(outf + idx) = rl;
        } else if constexpr (EPI == 2) {
          const uint2 ab = *reinterpret_cast<const uint2*>(addb + idx);
          v[0] += bflo(ab.x); v[1] += bfhi(ab.x);
          v[2] += bflo(ab.y); v[3] += bfhi(ab.y);
          uint2 o; o.x = pack2bf(v[0], v[1]); o.y = pack2bf(v[2], v[3]);
          *reinterpret_cast<uint2*>(outb0 + idx) = o;
        } else {
          const uint2 ab = *reinterpret_cast<const uint2*>(addb + idx);
          v[0] += bflo(ab.x); v[1] += bfhi(ab.x);
          v[2] += bflo(ab.y); v[3] += bfhi(ab.y);
          float4 rl = {relu(v[0]), relu(v[1]), relu(v[2]), relu(v[3])};
          *reinterpret_cast<float4*>(outf + idx) = rl;
        }
      }
    }

    if (!hn) break;
    __syncthreads();
    tile = nxt;
    cur ^= 1;
  }
}

__global__ __launch_bounds__(256) void mol_mean(const float* __restrict__ dfin,
                                                float* __restrict__ out) {
  int mol = blockIdx.x, c = threadIdx.x;
  const float* p = dfin + (size_t)mol * (42 * 256) + c;
  float s = 0.f;
#pragma unroll
  for (int a = 0; a < 42; ++a) s += p[a * 256];
  out[(size_t)mol * 256 + c] = s * (1.0f / 42.0f);
}

extern "C" void kernel_launch(void* const* d_in, const int* in_sizes, int n_in,
                              void* d_out, int out_size, void* d_ws,
                              size_t ws_size, hipStream_t stream) {
  const float* f_atoms = (const float*)d_in[0];
  const float* f_bonds = (const float*)d_in[1];
  const float* W_i = (const float*)d_in[2];
  const float* W_h = (const float*)d_in[3];
  const float* W_o = (const float*)d_in[4];
  const float* b_o = (const float*)d_in[5];
  const int* a2b = (const int*)d_in[6];
  const int* b2a = (const int*)d_in[7];
  const int* b2revb = (const int*)d_in[8];

  const int NA = 168000, NB = 360000, H = 256;
  const size_t SZ_BH = (size_t)NB * H * 2;
  const size_t SZ_AH = (size_t)NA * H * 2;

  char* ws = (char*)d_ws;
  u16* inp_b = (u16*)ws;  ws += SZ_BH;   // S_0 (pre-act bond state = inp)
  u16* P0    = (u16*)ws;  ws += SZ_BH;   // S_1
  u16* P1    = (u16*)ws;  ws += SZ_BH;   // S_2
  u16* amsg  = (u16*)ws;  ws += SZ_AH;
  u16* base_b = (u16*)ws; ws += SZ_AH;
  u16* Wi_b  = (u16*)ws;  ws += 256 * 160 * 2;
  u16* Wh_b  = (u16*)ws;  ws += 256 * 256 * 2;
  u16* Wo1_b = (u16*)ws;  ws += 256 * 160 * 2;
  u16* Wo2_b = (u16*)ws;  ws += 256 * 256 * 2;

  float* out = (float*)d_out;
  float* d0 = out;
  float* d1 = d0 + (size_t)NA * H;
  float* d2 = d1 + (size_t)NA * H;
  float* dfin = d2 + (size_t)NA * H;
  float* mol = dfin + (size_t)NA * H;

  dim3 blk(256);
  const int GRID = 1024;  // 4 blocks/CU target; persistent grid-stride
  const int ntB = NB / 32, ntA = NA / 32;

  cvt_all<<<dim3(832), blk, 0, stream>>>(W_i, W_h, W_o, Wi_b, Wh_b, Wo1_b, Wo2_b);

  // inp = f_bonds @ W_i^T  (pre-activation; relu fused into consumers)
  gemm8<0, 0, 160, 0, 4><<<dim3(GRID), blk, 0, stream>>>(
      f_bonds, 147, nullptr, nullptr, nullptr, nullptr, Wi_b,
      nullptr, nullptr, inp_b, nullptr, nullptr, ntB);
  // base = f_atoms @ W_o1^T + b_o (pre-relu, bf16) ; d0 = relu(base) f32
  gemm8<0, 1, 160, 0, 4><<<dim3(GRID), blk, 0, stream>>>(
      f_atoms, 133, nullptr, nullptr, nullptr, nullptr, Wo1_b,
      nullptr, b_o, base_b, d0, nullptr, ntA);

  u16* S = inp_b;
  u16* pms[2] = {P0, P1};
  float* douts[3] = {d1, d2, dfin};
  for (int d = 0; d < 3; ++d) {
    if (d < 2) {
      // d_{d+1} = relu(base + (gather-sum) @ W_o2^T); amsg written as side-out
      gemm8<3, 3, 256, 1, 2><<<dim3(GRID), blk, 0, stream>>>(
          nullptr, 0, S, nullptr, a2b, nullptr, Wo2_b,
          base_b, nullptr, nullptr, douts[d], amsg, ntA);
      // S' = inp + (amsg[b2a] - relu(S[b2revb])) @ W_h^T  (gather fused)
      gemm8<2, 2, 256, 0, 4><<<dim3(GRID), blk, 0, stream>>>(
          nullptr, 0, amsg, S, b2a, b2revb, Wh_b,
          inp_b, nullptr, pms[d], nullptr, nullptr, ntB);
      S = pms[d];
    } else {
      gemm8<3, 3, 256, 0, 2><<<dim3(GRID), blk, 0, stream>>>(
          nullptr, 0, S, nullptr, a2b, nullptr, Wo2_b,
          base_b, nullptr, nullptr, douts[d], nullptr, ntA);
    }
  }
  mol_mean<<<dim3(4000), blk, 0, stream>>>(dfin, mol);
}

// Round 10
// 1915.715 us; speedup vs baseline: 1.0334x; 1.0334x over previous
//
#include <hip/hip_runtime.h>

typedef unsigned short u16;
typedef unsigned int u32;
typedef __bf16 bf16x8 __attribute__((ext_vector_type(8)));
typedef float f32x4 __attribute__((ext_vector_type(4)));

__device__ __forceinline__ float bf2f(u16 h) {
  union { u32 u; float f; } c; c.u = ((u32)h) << 16; return c.f;
}
__device__ __forceinline__ float bflo(u32 u) {
  union { u32 u; float f; } c; c.u = u << 16; return c.f;
}
__device__ __forceinline__ float bfhi(u32 u) {
  union { u32 u; float f; } c; c.u = u & 0xffff0000u; return c.f;
}
// compiler emits packed v_cvt_pk_bf16_f32 for __bf16 casts (RNE)
__device__ __forceinline__ u32 pack2bf(float a, float b) {
  union { __bf16 h[2]; u32 u; } c; c.h[0] = (__bf16)a; c.h[1] = (__bf16)b;
  return c.u;
}
__device__ __forceinline__ u16 f2bf(float f) {
  union { __bf16 h; u16 u; } c; c.h = (__bf16)f; return c.u;
}
__device__ __forceinline__ float relu(float x) { return x > 0.f ? x : 0.f; }

// One-shot conversion of all four weight slices to bf16 [N][Kpad] layouts.
__global__ __launch_bounds__(256) void cvt_all(
    const float* __restrict__ Wi, const float* __restrict__ Wh,
    const float* __restrict__ Wo, u16* __restrict__ dWi, u16* __restrict__ dWh,
    u16* __restrict__ dWo1, u16* __restrict__ dWo2) {
  int i = blockIdx.x * 256 + threadIdx.x;
  if (i < 40960) {
    int n = i / 160, k = i % 160;
    dWi[i] = f2bf(k < 147 ? Wi[n * 147 + k] : 0.f);
  } else if (i < 106496) {
    int j = i - 40960;
    dWh[j] = f2bf(Wh[j]);
  } else if (i < 147456) {
    int j = i - 106496;
    int n = j / 160, k = j % 160;
    dWo1[j] = f2bf(k < 133 ? Wo[n * 389 + k] : 0.f);
  } else {
    int j = i - 147456;
    int n = j / 256, k = j % 256;
    dWo2[j] = f2bf(Wo[n * 389 + 133 + k]);
  }
}

// GEMM: C[M,256] = A[M,K] * W[256,K]^T.  BM=64, BN=256; 8 waves of 512-thread
// block, wave = 32 rows x 64-col band (acc[2][4] = 32 VGPRs -> <=128 VGPR,
// 4 waves/SIMD occupancy).  A staged COALESCED into LDS once (1 barrier, no
// cross-phase staging regs: r3/r9 spill lesson).  B-fragments from global
// (weights L2-resident).  Swapped-operand MFMA: lane holds 4 consecutive
// output cols (c0 = wn + jw*16 + (lane>>4)*4) at row m0+rh*32+im*16+(lane&15).
// Stores: bf16 = 8B uint2, f32 = 16B float4 (partial lines merge in L2).
// Output must not alias any input (cross-wave WAR, round-4 lesson).
// ASRC: 0 = A from f32 global [M][Kreal] (k<Kreal guard, converted)
//       2 = A row r = bf16( Ab[idx1[r]] - relu(Ab2[idx2[r]]) )  [KPAD=256]
//       3 = A row r = bf16( sum_{j<6} relu(Ab[idx1[r*6+j]]) )   [KPAD=256]
//           (chunk-serial, register-light; if WAMSG also store to amsg_out)
// EPI:  0 = bf16 acc -> outb0
//       1 = v=acc+bias[c]; bf16 v -> outb0; relu(v) f32 -> outf
//       2 = v=acc+bf2f(addb[idx]); bf16 v -> outb0
//       3 = v=acc+bf2f(addb[idx]); relu(v) f32 -> outf
template <int ASRC, int EPI, int KPAD, int WAMSG>
__global__ __launch_bounds__(512, 4) void gemm10(
    const float* __restrict__ Af, int Kreal,
    const u16* __restrict__ Ab, const u16* __restrict__ Ab2,
    const int* __restrict__ idx1, const int* __restrict__ idx2,
    const u16* __restrict__ Bw,
    const u16* __restrict__ addb, const float* __restrict__ bias,
    u16* __restrict__ outb0, float* __restrict__ outf,
    u16* __restrict__ amsg_out) {
  constexpr int LDK = KPAD + 8;  // row stride 336/528B: banks spread, ~free
  __shared__ u16 As[64 * LDK];

  const int tid = threadIdx.x;
  const int lane = tid & 63, wid = tid >> 6;
  const int rh = wid >> 2;           // row half: 0 -> rows 0..31, 1 -> 32..63
  const int wn = (wid & 3) * 64;     // column band
  const int m0 = blockIdx.x * 64;
  const int lm = lane & 15, lg = lane >> 4;
  const int koff = lg * 8;

  // ---- coalesced staging of A[64][KPAD], no cross-phase registers ----
  if constexpr (ASRC == 0) {
#pragma unroll
    for (int p = 0; p < 64 * KPAD / 1024; ++p) {
      int e = (p * 512 + tid) * 2;
      int row = e / KPAD, k = e % KPAD;
      const float* src = Af + (size_t)(m0 + row) * Kreal + k;
      float x0 = (k < Kreal) ? src[0] : 0.f;
      float x1 = (k + 1 < Kreal) ? src[1] : 0.f;
      *reinterpret_cast<u32*>(&As[row * LDK + k]) = pack2bf(x0, x1);
    }
  } else if constexpr (ASRC == 2) {
    // fused gather-subtract: 8 threads/row, 32-u16 (64B) segment each
    static_assert(KPAD == 256, "ASRC2 assumes KPAD=256");
    const int row = tid >> 3, seg = tid & 7;
    const int gr = m0 + row;
    const u16* pa = Ab + (size_t)idx1[gr] * 256 + seg * 32;
    const u16* pb = Ab2 + (size_t)idx2[gr] * 256 + seg * 32;
    uint4 va[4], vb[4];
#pragma unroll
    for (int i = 0; i < 4; ++i) {
      va[i] = *reinterpret_cast<const uint4*>(pa + i * 8);
      vb[i] = *reinterpret_cast<const uint4*>(pb + i * 8);
    }
    u16* dst = &As[row * LDK + seg * 32];
#pragma unroll
    for (int i = 0; i < 4; ++i) {
      uint4 o;
      o.x = pack2bf(bflo(va[i].x) - relu(bflo(vb[i].x)),
                    bfhi(va[i].x) - relu(bfhi(vb[i].x)));
      o.y = pack2bf(bflo(va[i].y) - relu(bflo(vb[i].y)),
                    bfhi(va[i].y) - relu(bfhi(vb[i].y)));
      o.z = pack2bf(bflo(va[i].z) - relu(bflo(vb[i].z)),
                    bfhi(va[i].z) - relu(bfhi(vb[i].z)));
      o.w = pack2bf(bflo(va[i].w) - relu(bflo(vb[i].w)),
                    bfhi(va[i].w) - relu(bfhi(vb[i].w)));
      *reinterpret_cast<uint4*>(dst + i * 8) = o;
    }
  } else {
    // fused gather_sum: 8 threads/row, chunk-serial (register-light);
    // per 8-elem chunk all 6 neighbor loads issued together.
    static_assert(KPAD == 256, "ASRC3 assumes KPAD=256");
    const int row = tid >> 3, seg = tid & 7;
    const int gr = m0 + row;
    const int* nbp = idx1 + gr * 6;
    int nn[6];
#pragma unroll
    for (int j = 0; j < 6; ++j) nn[j] = nbp[j];
    const u16* base = Ab + seg * 32;
#pragma unroll
    for (int c = 0; c < 4; ++c) {
      const int off = c * 8;
      uint4 v[6];
#pragma unroll
      for (int j = 0; j < 6; ++j)
        v[j] = *reinterpret_cast<const uint4*>(base + (size_t)nn[j] * 256 + off);
      float s[8];
#pragma unroll
      for (int e = 0; e < 8; ++e) s[e] = 0.f;
#pragma unroll
      for (int j = 0; j < 6; ++j) {
        s[0] += relu(bflo(v[j].x)); s[1] += relu(bfhi(v[j].x));
        s[2] += relu(bflo(v[j].y)); s[3] += relu(bfhi(v[j].y));
        s[4] += relu(bflo(v[j].z)); s[5] += relu(bfhi(v[j].z));
        s[6] += relu(bflo(v[j].w)); s[7] += relu(bfhi(v[j].w));
      }
      uint4 o;
      o.x = pack2bf(s[0], s[1]); o.y = pack2bf(s[2], s[3]);
      o.z = pack2bf(s[4], s[5]); o.w = pack2bf(s[6], s[7]);
      *reinterpret_cast<uint4*>(&As[row * LDK + seg * 32 + off]) = o;
      if constexpr (WAMSG)
        *reinterpret_cast<uint4*>(amsg_out + (size_t)gr * 256 + seg * 32 + off) = o;
    }
  }
  __syncthreads();

  f32x4 acc[2][4];
#pragma unroll
  for (int i = 0; i < 2; ++i)
#pragma unroll
    for (int j = 0; j < 4; ++j) acc[i][j] = (f32x4)(0.f);

#pragma unroll
  for (int kk = 0; kk < KPAD / 32; ++kk) {
    const int k0 = kk * 32 + koff;
    bf16x8 a0 = *reinterpret_cast<const bf16x8*>(&As[(rh * 32 + lm) * LDK + k0]);
    bf16x8 a1 = *reinterpret_cast<const bf16x8*>(&As[(rh * 32 + 16 + lm) * LDK + k0]);
#pragma unroll
    for (int jw = 0; jw < 4; ++jw) {
      bf16x8 b = *reinterpret_cast<const bf16x8*>(
          Bw + (size_t)(wn + jw * 16 + lm) * KPAD + k0);
      acc[0][jw] = __builtin_amdgcn_mfma_f32_16x16x32_bf16(b, a0, acc[0][jw], 0, 0, 0);
      acc[1][jw] = __builtin_amdgcn_mfma_f32_16x16x32_bf16(b, a1, acc[1][jw], 0, 0, 0);
    }
  }

#pragma unroll
  for (int im = 0; im < 2; ++im) {
#pragma unroll
    for (int jw = 0; jw < 4; ++jw) {
      const int r = m0 + rh * 32 + im * 16 + lm;
      const int c0 = wn + jw * 16 + lg * 4;
      const size_t idx = (size_t)r * 256 + c0;
      f32x4 v = acc[im][jw];
      if constexpr (EPI == 0) {
        uint2 o; o.x = pack2bf(v[0], v[1]); o.y = pack2bf(v[2], v[3]);
        *reinterpret_cast<uint2*>(outb0 + idx) = o;
      } else if constexpr (EPI == 1) {
        const float4 bb = *reinterpret_cast<const float4*>(bias + c0);
        v[0] += bb.x; v[1] += bb.y; v[2] += bb.z; v[3] += bb.w;
        uint2 o; o.x = pack2bf(v[0], v[1]); o.y = pack2bf(v[2], v[3]);
        *reinterpret_cast<uint2*>(outb0 + idx) = o;
        float4 rl = {relu(v[0]), relu(v[1]), relu(v[2]), relu(v[3])};
        *reinterpret_cast<float4*>(outf + idx) = rl;
      } else if constexpr (EPI == 2) {
        const uint2 ab = *reinterpret_cast<const uint2*>(addb + idx);
        v[0] += bflo(ab.x); v[1] += bfhi(ab.x);
        v[2] += bflo(ab.y); v[3] += bfhi(ab.y);
        uint2 o; o.x = pack2bf(v[0], v[1]); o.y = pack2bf(v[2], v[3]);
        *reinterpret_cast<uint2*>(outb0 + idx) = o;
      } else {
        const uint2 ab = *reinterpret_cast<const uint2*>(addb + idx);
        v[0] += bflo(ab.x); v[1] += bfhi(ab.x);
        v[2] += bflo(ab.y); v[3] += bfhi(ab.y);
        float4 rl = {relu(v[0]), relu(v[1]), relu(v[2]), relu(v[3])};
        *reinterpret_cast<float4*>(outf + idx) = rl;
      }
    }
  }
}

__global__ __launch_bounds__(256) void mol_mean(const float* __restrict__ dfin,
                                                float* __restrict__ out) {
  int mol = blockIdx.x, c = threadIdx.x;
  const float* p = dfin + (size_t)mol * (42 * 256) + c;
  float s = 0.f;
#pragma unroll
  for (int a = 0; a < 42; ++a) s += p[a * 256];
  out[(size_t)mol * 256 + c] = s * (1.0f / 42.0f);
}

extern "C" void kernel_launch(void* const* d_in, const int* in_sizes, int n_in,
                              void* d_out, int out_size, void* d_ws,
                              size_t ws_size, hipStream_t stream) {
  const float* f_atoms = (const float*)d_in[0];
  const float* f_bonds = (const float*)d_in[1];
  const float* W_i = (const float*)d_in[2];
  const float* W_h = (const float*)d_in[3];
  const float* W_o = (const float*)d_in[4];
  const float* b_o = (const float*)d_in[5];
  const int* a2b = (const int*)d_in[6];
  const int* b2a = (const int*)d_in[7];
  const int* b2revb = (const int*)d_in[8];

  const int NA = 168000, NB = 360000, H = 256;
  const size_t SZ_BH = (size_t)NB * H * 2;
  const size_t SZ_AH = (size_t)NA * H * 2;

  char* ws = (char*)d_ws;
  u16* inp_b = (u16*)ws;  ws += SZ_BH;   // S_0 (pre-act bond state = inp)
  u16* P0    = (u16*)ws;  ws += SZ_BH;   // S_1
  u16* P1    = (u16*)ws;  ws += SZ_BH;   // S_2
  u16* amsg  = (u16*)ws;  ws += SZ_AH;
  u16* base_b = (u16*)ws; ws += SZ_AH;
  u16* Wi_b  = (u16*)ws;  ws += 256 * 160 * 2;
  u16* Wh_b  = (u16*)ws;  ws += 256 * 256 * 2;
  u16* Wo1_b = (u16*)ws;  ws += 256 * 160 * 2;
  u16* Wo2_b = (u16*)ws;  ws += 256 * 256 * 2;

  float* out = (float*)d_out;
  float* d0 = out;
  float* d1 = d0 + (size_t)NA * H;
  float* d2 = d1 + (size_t)NA * H;
  float* dfin = d2 + (size_t)NA * H;
  float* mol = dfin + (size_t)NA * H;

  dim3 blk(512);
  cvt_all<<<dim3(832), dim3(256), 0, stream>>>(W_i, W_h, W_o, Wi_b, Wh_b, Wo1_b, Wo2_b);

  // inp = f_bonds @ W_i^T  (pre-activation; relu fused into consumers)
  gemm10<0, 0, 160, 0><<<dim3(NB / 64), blk, 0, stream>>>(
      f_bonds, 147, nullptr, nullptr, nullptr, nullptr, Wi_b,
      nullptr, nullptr, inp_b, nullptr, nullptr);
  // base = f_atoms @ W_o1^T + b_o (pre-relu, bf16) ; d0 = relu(base) f32
  gemm10<0, 1, 160, 0><<<dim3(NA / 64), blk, 0, stream>>>(
      f_atoms, 133, nullptr, nullptr, nullptr, nullptr, Wo1_b,
      nullptr, b_o, base_b, d0, nullptr);

  u16* S = inp_b;
  u16* pms[2] = {P0, P1};
  float* douts[3] = {d1, d2, dfin};
  for (int d = 0; d < 3; ++d) {
    if (d < 2) {
      // d_{d+1} = relu(base + (gather-sum) @ W_o2^T); amsg written as side-out
      gemm10<3, 3, 256, 1><<<dim3(NA / 64), blk, 0, stream>>>(
          nullptr, 0, S, nullptr, a2b, nullptr, Wo2_b,
          base_b, nullptr, nullptr, douts[d], amsg);
      // S' = inp + (amsg[b2a] - relu(S[b2revb])) @ W_h^T  (gather fused)
      gemm10<2, 2, 256, 0><<<dim3(NB / 64), blk, 0, stream>>>(
          nullptr, 0, amsg, S, b2a, b2revb, Wh_b,
          inp_b, nullptr, pms[d], nullptr, nullptr);
      S = pms[d];
    } else {
      gemm10<3, 3, 256, 0><<<dim3(NA / 64), blk, 0, stream>>>(
          nullptr, 0, S, nullptr, a2b, nullptr, Wo2_b,
          base_b, nullptr, nullptr, douts[d], nullptr);
    }
  }
  mol_mean<<<dim3(4000), dim3(256), 0, stream>>>(dfin, mol);
}

// Round 11
// 1819.466 us; speedup vs baseline: 1.0881x; 1.0529x over previous
//
#include <hip/hip_runtime.h>

typedef unsigned short u16;
typedef unsigned int u32;
typedef __bf16 bf16x8 __attribute__((ext_vector_type(8)));
typedef float f32x4 __attribute__((ext_vector_type(4)));

__device__ __forceinline__ float bf2f(u16 h) {
  union { u32 u; float f; } c; c.u = ((u32)h) << 16; return c.f;
}
__device__ __forceinline__ float bflo(u32 u) {
  union { u32 u; float f; } c; c.u = u << 16; return c.f;
}
__device__ __forceinline__ float bfhi(u32 u) {
  union { u32 u; float f; } c; c.u = u & 0xffff0000u; return c.f;
}
// compiler emits packed v_cvt_pk_bf16_f32 for __bf16 casts (RNE)
__device__ __forceinline__ u32 pack2bf(float a, float b) {
  union { __bf16 h[2]; u32 u; } c; c.h[0] = (__bf16)a; c.h[1] = (__bf16)b;
  return c.u;
}
__device__ __forceinline__ u16 f2bf(float f) {
  union { __bf16 h; u16 u; } c; c.h = (__bf16)f; return c.u;
}
__device__ __forceinline__ float relu(float x) { return x > 0.f ? x : 0.f; }

// One-shot conversion of all four weight slices to bf16 [N][Kpad] layouts.
__global__ __launch_bounds__(256) void cvt_all(
    const float* __restrict__ Wi, const float* __restrict__ Wh,
    const float* __restrict__ Wo, u16* __restrict__ dWi, u16* __restrict__ dWh,
    u16* __restrict__ dWo1, u16* __restrict__ dWo2) {
  int i = blockIdx.x * 256 + threadIdx.x;
  if (i < 40960) {
    int n = i / 160, k = i % 160;
    dWi[i] = f2bf(k < 147 ? Wi[n * 147 + k] : 0.f);
  } else if (i < 106496) {
    int j = i - 40960;
    dWh[j] = f2bf(Wh[j]);
  } else if (i < 147456) {
    int j = i - 106496;
    int n = j / 160, k = j % 160;
    dWo1[j] = f2bf(k < 133 ? Wo[n * 389 + k] : 0.f);
  } else {
    int j = i - 147456;
    int n = j / 256, k = j % 256;
    dWo2[j] = f2bf(Wo[n * 389 + 133 + k]);
  }
}

// GEMM: C[M,256] = A[M,K] * W[256,K]^T.  BM=32, BN=256; 256 threads = 4
// waves, each wave 32 rows x 64-col band (acc[2][4] = 32 VGPRs).  One-shot
// block: A staged COALESCED into LDS once, ONE 4-wave barrier, compute, exit.
// LDS 17KB + launch_bounds(256,6) -> 6 independent blocks/CU: stage-phase of
// some blocks overlaps compute-phase of others (r10 lesson: small barrier
// domains + more independent blocks, not more waves per barrier).
// B-fragments from global (weights L2-resident).  Swapped-operand MFMA:
// lane holds 4 consecutive output cols at row m0+im*16+(lane&15).
// Stores: bf16 = 8B uint2, f32 = 16B float4.  Output must not alias any
// input (cross-wave WAR, round-4 lesson).  No cross-phase staging registers
// (r3/r9 spill lesson).
// ASRC: 0 = A from f32 global [M][Kreal] (k<Kreal guard, converted, KPAD=160)
//       2 = A row r = bf16( Ab[idx1[r]] - relu(Ab2[idx2[r]]) )  [KPAD=256]
//       3 = A row r = bf16( sum_{j<6} relu(Ab[idx1[r*6+j]]) )   [KPAD=256]
//           (chunk-serial, register-light; if WAMSG also store to amsg_out)
// EPI:  0 = bf16 acc -> outb0
//       1 = v=acc+bias[c]; bf16 v -> outb0; relu(v) f32 -> outf
//       2 = v=acc+bf2f(addb[idx]); bf16 v -> outb0
//       3 = v=acc+bf2f(addb[idx]); relu(v) f32 -> outf
template <int ASRC, int EPI, int KPAD, int WAMSG>
__global__ __launch_bounds__(256, 6) void gemm11(
    const float* __restrict__ Af, int Kreal,
    const u16* __restrict__ Ab, const u16* __restrict__ Ab2,
    const int* __restrict__ idx1, const int* __restrict__ idx2,
    const u16* __restrict__ Bw,
    const u16* __restrict__ addb, const float* __restrict__ bias,
    u16* __restrict__ outb0, float* __restrict__ outf,
    u16* __restrict__ amsg_out) {
  constexpr int LDK = KPAD + 8;  // 16B-slot stride odd: 2-way bank alias, free
  __shared__ u16 As[32 * LDK];

  const int tid = threadIdx.x;
  const int lane = tid & 63;
  const int wn = (tid >> 6) * 64;   // wave's column band
  const int m0 = blockIdx.x * 32;
  const int lm = lane & 15, lg = lane >> 4;
  const int koff = lg * 8;

  // ---- coalesced staging of A[32][KPAD] ----
  if constexpr (ASRC == 0) {
    static_assert(ASRC != 0 || KPAD == 160, "ASRC0 map assumes KPAD=160");
#pragma unroll
    for (int p = 0; p < 10; ++p) {  // 32*160/2 pairs / 256 threads
      int e = (p * 256 + tid) * 2;
      int row = e / KPAD, k = e % KPAD;
      const float* src = Af + (size_t)(m0 + row) * Kreal + k;
      float x0 = (k < Kreal) ? src[0] : 0.f;
      float x1 = (k + 1 < Kreal) ? src[1] : 0.f;
      *reinterpret_cast<u32*>(&As[row * LDK + k]) = pack2bf(x0, x1);
    }
  } else if constexpr (ASRC == 2) {
    // fused gather-subtract: 8 threads/row, 32-u16 (64B) segment each
    static_assert(KPAD == 256, "ASRC2 assumes KPAD=256");
    const int row = tid >> 3, seg = tid & 7;
    const int gr = m0 + row;
    const u16* pa = Ab + (size_t)idx1[gr] * 256 + seg * 32;
    const u16* pb = Ab2 + (size_t)idx2[gr] * 256 + seg * 32;
    uint4 va[4], vb[4];
#pragma unroll
    for (int i = 0; i < 4; ++i) {
      va[i] = *reinterpret_cast<const uint4*>(pa + i * 8);
      vb[i] = *reinterpret_cast<const uint4*>(pb + i * 8);
    }
    u16* dst = &As[row * LDK + seg * 32];
#pragma unroll
    for (int i = 0; i < 4; ++i) {
      uint4 o;
      o.x = pack2bf(bflo(va[i].x) - relu(bflo(vb[i].x)),
                    bfhi(va[i].x) - relu(bfhi(vb[i].x)));
      o.y = pack2bf(bflo(va[i].y) - relu(bflo(vb[i].y)),
                    bfhi(va[i].y) - relu(bfhi(vb[i].y)));
      o.z = pack2bf(bflo(va[i].z) - relu(bflo(vb[i].z)),
                    bfhi(va[i].z) - relu(bfhi(vb[i].z)));
      o.w = pack2bf(bflo(va[i].w) - relu(bflo(vb[i].w)),
                    bfhi(va[i].w) - relu(bfhi(vb[i].w)));
      *reinterpret_cast<uint4*>(dst + i * 8) = o;
    }
  } else {
    // fused gather_sum: 8 threads/row, chunk-serial (register-light);
    // per 8-elem chunk all 6 neighbor loads issued together.
    static_assert(KPAD == 256, "ASRC3 assumes KPAD=256");
    const int row = tid >> 3, seg = tid & 7;
    const int gr = m0 + row;
    const int* nbp = idx1 + gr * 6;
    int nn[6];
#pragma unroll
    for (int j = 0; j < 6; ++j) nn[j] = nbp[j];
    const u16* base = Ab + seg * 32;
#pragma unroll
    for (int c = 0; c < 4; ++c) {
      const int off = c * 8;
      uint4 v[6];
#pragma unroll
      for (int j = 0; j < 6; ++j)
        v[j] = *reinterpret_cast<const uint4*>(base + (size_t)nn[j] * 256 + off);
      float s[8];
#pragma unroll
      for (int e = 0; e < 8; ++e) s[e] = 0.f;
#pragma unroll
      for (int j = 0; j < 6; ++j) {
        s[0] += relu(bflo(v[j].x)); s[1] += relu(bfhi(v[j].x));
        s[2] += relu(bflo(v[j].y)); s[3] += relu(bfhi(v[j].y));
        s[4] += relu(bflo(v[j].z)); s[5] += relu(bfhi(v[j].z));
        s[6] += relu(bflo(v[j].w)); s[7] += relu(bfhi(v[j].w));
      }
      uint4 o;
      o.x = pack2bf(s[0], s[1]); o.y = pack2bf(s[2], s[3]);
      o.z = pack2bf(s[4], s[5]); o.w = pack2bf(s[6], s[7]);
      *reinterpret_cast<uint4*>(&As[row * LDK + seg * 32 + off]) = o;
      if constexpr (WAMSG)
        *reinterpret_cast<uint4*>(amsg_out + (size_t)gr * 256 + seg * 32 + off) = o;
    }
  }
  __syncthreads();

  f32x4 acc[2][4];
#pragma unroll
  for (int i = 0; i < 2; ++i)
#pragma unroll
    for (int j = 0; j < 4; ++j) acc[i][j] = (f32x4)(0.f);

#pragma unroll
  for (int kk = 0; kk < KPAD / 32; ++kk) {
    const int k0 = kk * 32 + koff;
    bf16x8 a0 = *reinterpret_cast<const bf16x8*>(&As[lm * LDK + k0]);
    bf16x8 a1 = *reinterpret_cast<const bf16x8*>(&As[(16 + lm) * LDK + k0]);
#pragma unroll
    for (int jw = 0; jw < 4; ++jw) {
      bf16x8 b = *reinterpret_cast<const bf16x8*>(
          Bw + (size_t)(wn + jw * 16 + lm) * KPAD + k0);
      acc[0][jw] = __builtin_amdgcn_mfma_f32_16x16x32_bf16(b, a0, acc[0][jw], 0, 0, 0);
      acc[1][jw] = __builtin_amdgcn_mfma_f32_16x16x32_bf16(b, a1, acc[1][jw], 0, 0, 0);
    }
  }

#pragma unroll
  for (int im = 0; im < 2; ++im) {
#pragma unroll
    for (int jw = 0; jw < 4; ++jw) {
      const int r = m0 + im * 16 + lm;
      const int c0 = wn + jw * 16 + lg * 4;
      const size_t idx = (size_t)r * 256 + c0;
      f32x4 v = acc[im][jw];
      if constexpr (EPI == 0) {
        uint2 o; o.x = pack2bf(v[0], v[1]); o.y = pack2bf(v[2], v[3]);
        *reinterpret_cast<uint2*>(outb0 + idx) = o;
      } else if constexpr (EPI == 1) {
        const float4 bb = *reinterpret_cast<const float4*>(bias + c0);
        v[0] += bb.x; v[1] += bb.y; v[2] += bb.z; v[3] += bb.w;
        uint2 o; o.x = pack2bf(v[0], v[1]); o.y = pack2bf(v[2], v[3]);
        *reinterpret_cast<uint2*>(outb0 + idx) = o;
        float4 rl = {relu(v[0]), relu(v[1]), relu(v[2]), relu(v[3])};
        *reinterpret_cast<float4*>(outf + idx) = rl;
      } else if constexpr (EPI == 2) {
        const uint2 ab = *reinterpret_cast<const uint2*>(addb + idx);
        v[0] += bflo(ab.x); v[1] += bfhi(ab.x);
        v[2] += bflo(ab.y); v[3] += bfhi(ab.y);
        uint2 o; o.x = pack2bf(v[0], v[1]); o.y = pack2bf(v[2], v[3]);
        *reinterpret_cast<uint2*>(outb0 + idx) = o;
      } else {
        const uint2 ab = *reinterpret_cast<const uint2*>(addb + idx);
        v[0] += bflo(ab.x); v[1] += bfhi(ab.x);
        v[2] += bflo(ab.y); v[3] += bfhi(ab.y);
        float4 rl = {relu(v[0]), relu(v[1]), relu(v[2]), relu(v[3])};
        *reinterpret_cast<float4*>(outf + idx) = rl;
      }
    }
  }
}

__global__ __launch_bounds__(256) void mol_mean(const float* __restrict__ dfin,
                                                float* __restrict__ out) {
  int mol = blockIdx.x, c = threadIdx.x;
  const float* p = dfin + (size_t)mol * (42 * 256) + c;
  float s = 0.f;
#pragma unroll
  for (int a = 0; a < 42; ++a) s += p[a * 256];
  out[(size_t)mol * 256 + c] = s * (1.0f / 42.0f);
}

extern "C" void kernel_launch(void* const* d_in, const int* in_sizes, int n_in,
                              void* d_out, int out_size, void* d_ws,
                              size_t ws_size, hipStream_t stream) {
  const float* f_atoms = (const float*)d_in[0];
  const float* f_bonds = (const float*)d_in[1];
  const float* W_i = (const float*)d_in[2];
  const float* W_h = (const float*)d_in[3];
  const float* W_o = (const float*)d_in[4];
  const float* b_o = (const float*)d_in[5];
  const int* a2b = (const int*)d_in[6];
  const int* b2a = (const int*)d_in[7];
  const int* b2revb = (const int*)d_in[8];

  const int NA = 168000, NB = 360000, H = 256;
  const size_t SZ_BH = (size_t)NB * H * 2;
  const size_t SZ_AH = (size_t)NA * H * 2;

  char* ws = (char*)d_ws;
  u16* inp_b = (u16*)ws;  ws += SZ_BH;   // S_0 (pre-act bond state = inp)
  u16* P0    = (u16*)ws;  ws += SZ_BH;   // S_1
  u16* P1    = (u16*)ws;  ws += SZ_BH;   // S_2
  u16* amsg  = (u16*)ws;  ws += SZ_AH;
  u16* base_b = (u16*)ws; ws += SZ_AH;
  u16* Wi_b  = (u16*)ws;  ws += 256 * 160 * 2;
  u16* Wh_b  = (u16*)ws;  ws += 256 * 256 * 2;
  u16* Wo1_b = (u16*)ws;  ws += 256 * 160 * 2;
  u16* Wo2_b = (u16*)ws;  ws += 256 * 256 * 2;

  float* out = (float*)d_out;
  float* d0 = out;
  float* d1 = d0 + (size_t)NA * H;
  float* d2 = d1 + (size_t)NA * H;
  float* dfin = d2 + (size_t)NA * H;
  float* mol = dfin + (size_t)NA * H;

  dim3 blk(256);
  cvt_all<<<dim3(832), blk, 0, stream>>>(W_i, W_h, W_o, Wi_b, Wh_b, Wo1_b, Wo2_b);

  // inp = f_bonds @ W_i^T  (pre-activation; relu fused into consumers)
  gemm11<0, 0, 160, 0><<<dim3(NB / 32), blk, 0, stream>>>(
      f_bonds, 147, nullptr, nullptr, nullptr, nullptr, Wi_b,
      nullptr, nullptr, inp_b, nullptr, nullptr);
  // base = f_atoms @ W_o1^T + b_o (pre-relu, bf16) ; d0 = relu(base) f32
  gemm11<0, 1, 160, 0><<<dim3(NA / 32), blk, 0, stream>>>(
      f_atoms, 133, nullptr, nullptr, nullptr, nullptr, Wo1_b,
      nullptr, b_o, base_b, d0, nullptr);

  u16* S = inp_b;
  u16* pms[2] = {P0, P1};
  float* douts[3] = {d1, d2, dfin};
  for (int d = 0; d < 3; ++d) {
    if (d < 2) {
      // d_{d+1} = relu(base + (gather-sum) @ W_o2^T); amsg written as side-out
      gemm11<3, 3, 256, 1><<<dim3(NA / 32), blk, 0, stream>>>(
          nullptr, 0, S, nullptr, a2b, nullptr, Wo2_b,
          base_b, nullptr, nullptr, douts[d], amsg);
      // S' = inp + (amsg[b2a] - relu(S[b2revb])) @ W_h^T  (gather fused)
      gemm11<2, 2, 256, 0><<<dim3(NB / 32), blk, 0, stream>>>(
          nullptr, 0, amsg, S, b2a, b2revb, Wh_b,
          inp_b, nullptr, pms[d], nullptr, nullptr);
      S = pms[d];
    } else {
      gemm11<3, 3, 256, 0><<<dim3(NA / 32), blk, 0, stream>>>(
          nullptr, 0, S, nullptr, a2b, nullptr, Wo2_b,
          base_b, nullptr, nullptr, douts[d], nullptr);
    }
  }
  mol_mean<<<dim3(4000), blk, 0, stream>>>(dfin, mol);
}

// Round 12
// 1663.525 us; speedup vs baseline: 1.1901x; 1.0937x over previous
//
#include <hip/hip_runtime.h>

typedef unsigned short u16;
typedef unsigned int u32;
typedef __bf16 bf16x8 __attribute__((ext_vector_type(8)));
typedef float f32x4 __attribute__((ext_vector_type(4)));

__device__ __forceinline__ float bf2f(u16 h) {
  union { u32 u; float f; } c; c.u = ((u32)h) << 16; return c.f;
}
__device__ __forceinline__ float bflo(u32 u) {
  union { u32 u; float f; } c; c.u = u << 16; return c.f;
}
__device__ __forceinline__ float bfhi(u32 u) {
  union { u32 u; float f; } c; c.u = u & 0xffff0000u; return c.f;
}
__device__ __forceinline__ u32 pack2bf(float a, float b) {
  union { __bf16 h[2]; u32 u; } c; c.h[0] = (__bf16)a; c.h[1] = (__bf16)b;
  return c.u;
}
__device__ __forceinline__ u16 f2bf(float f) {
  union { __bf16 h; u16 u; } c; c.h = (__bf16)f; return c.u;
}
__device__ __forceinline__ float relu(float x) { return x > 0.f ? x : 0.f; }

// async 16B global->LDS DMA (per-lane global src, wave-uniform LDS base;
// HW writes base + lane*16). Drained by __syncthreads() (vmcnt in barrier).
typedef __attribute__((address_space(1))) const u32* gas_t;
typedef __attribute__((address_space(3))) u32* las_t;
__device__ __forceinline__ void async16(const void* g, void* l) {
  __builtin_amdgcn_global_load_lds((gas_t)g, (las_t)l, 16, 0, 0);
}

// Weights -> bf16 [256][Kpad] (W_i->160, W_h->256, W_o1->160, W_o2->256).
__global__ __launch_bounds__(256) void cvt_all(
    const float* __restrict__ Wi, const float* __restrict__ Wh,
    const float* __restrict__ Wo, u16* __restrict__ dWi, u16* __restrict__ dWh,
    u16* __restrict__ dWo1, u16* __restrict__ dWo2) {
  int i = blockIdx.x * 256 + threadIdx.x;
  if (i < 40960) {
    int n = i / 160, k = i % 160;
    dWi[i] = f2bf(k < 147 ? Wi[n * 147 + k] : 0.f);
  } else if (i < 106496) {
    int j = i - 40960;
    dWh[j] = f2bf(Wh[j]);
  } else if (i < 147456) {
    int j = i - 106496;
    int n = j / 160, k = j % 160;
    dWo1[j] = f2bf(k < 133 ? Wo[n * 389 + k] : 0.f);
  } else {
    int j = i - 147456;
    int n = j / 256, k = j % 256;
    dWo2[j] = f2bf(Wo[n * 389 + 133 + k]);
  }
}

// f32 [M][Ks] -> bf16 [M][Kd] zero-padded.
__global__ __launch_bounds__(256) void cvt_feat(const float* __restrict__ src,
                                                u16* __restrict__ dst,
                                                int Ks, int Kd, long total) {
  long i = (long)blockIdx.x * 256 + threadIdx.x;
  if (i >= total) return;
  int row = (int)(i / Kd), k = (int)(i % Kd);
  dst[i] = f2bf(k < Ks ? src[(size_t)row * Ks + k] : 0.f);
}

// Async linear-A GEMM: C[M,256] = A[M,KPAD] * W[256,KPAD]^T.
// BM=64, 4 waves x (64 rows x 64-col band), acc[4][4].  A staged by pure
// global_load_lds (16B, zero staging VALU, no VGPR round-trip); LDS layout
// forced linear -> bank-conflict fix is SOURCE-side chunk XOR swizzle
// (k8 ^= row&XM) mirrored on fragment reads (rule #21 both-sides).
// B-fragments from global (L2-resident).  Swapped-operand MFMA epilogue:
// lane holds 4 consecutive output cols; bf16 8B / f32 16B stores.
// EPI: 0 = bf16 acc -> outb0 AND bf16 relu(acc) -> outb1      (W_i)
//      1 = v=acc+bias; bf16 v -> outb0; relu(v) f32 -> outf   (W_o1)
//      3 = v=acc+bf2f(addb[idx]); relu(v) f32 -> outf         (W_o2)
template <int KPAD, int EPI>
__global__ __launch_bounds__(256, 4) void gemm_async(
    const u16* __restrict__ Ab, const u16* __restrict__ Bw,
    const u16* __restrict__ addb, const float* __restrict__ bias,
    u16* __restrict__ outb0, u16* __restrict__ outb1,
    float* __restrict__ outf) {
  constexpr int CPR = KPAD / 8;              // 16B chunks per row
  constexpr int XM = (KPAD == 256) ? 7 : 3;  // source-swizzle mask
  constexpr int IPW = CPR / 4;               // gload_lds instrs per wave
  __shared__ u16 As[64 * KPAD];

  const int tid = threadIdx.x;
  const int lane = tid & 63, wid = tid >> 6;
  const int wn = wid * 64;
  const int m0 = blockIdx.x * 64;
  const int lm = lane & 15, lg = lane >> 4;

#pragma unroll
  for (int p = 0; p < IPW; ++p) {
    const int q = wid * IPW + p;
    const int chunk = q * 64 + lane;
    const int row = chunk / CPR, k8 = chunk % CPR;
    const u16* src = Ab + (size_t)(m0 + row) * KPAD + (k8 ^ (row & XM)) * 8;
    async16(src, &As[q * 512]);
  }
  __syncthreads();

  f32x4 acc[4][4];
#pragma unroll
  for (int i = 0; i < 4; ++i)
#pragma unroll
    for (int j = 0; j < 4; ++j) acc[i][j] = (f32x4)(0.f);

#pragma unroll
  for (int kk = 0; kk < KPAD / 32; ++kk) {
    bf16x8 a[4];
#pragma unroll
    for (int t = 0; t < 4; ++t) {
      const int row = t * 16 + lm;
      const int phys = (kk * 4 + lg) ^ (row & XM);
      a[t] = *reinterpret_cast<const bf16x8*>(&As[row * KPAD + phys * 8]);
    }
#pragma unroll
    for (int jw = 0; jw < 4; ++jw) {
      bf16x8 b = *reinterpret_cast<const bf16x8*>(
          Bw + (size_t)(wn + jw * 16 + lm) * KPAD + kk * 32 + lg * 8);
#pragma unroll
      for (int t = 0; t < 4; ++t)
        acc[t][jw] = __builtin_amdgcn_mfma_f32_16x16x32_bf16(b, a[t], acc[t][jw], 0, 0, 0);
    }
  }

#pragma unroll
  for (int im = 0; im < 4; ++im) {
#pragma unroll
    for (int jw = 0; jw < 4; ++jw) {
      const int r = m0 + im * 16 + lm;
      const int c0 = wn + jw * 16 + lg * 4;
      const size_t idx = (size_t)r * 256 + c0;
      f32x4 v = acc[im][jw];
      if constexpr (EPI == 0) {
        uint2 o; o.x = pack2bf(v[0], v[1]); o.y = pack2bf(v[2], v[3]);
        *reinterpret_cast<uint2*>(outb0 + idx) = o;
        uint2 m; m.x = pack2bf(relu(v[0]), relu(v[1]));
        m.y = pack2bf(relu(v[2]), relu(v[3]));
        *reinterpret_cast<uint2*>(outb1 + idx) = m;
      } else if constexpr (EPI == 1) {
        const float4 bb = *reinterpret_cast<const float4*>(bias + c0);
        v[0] += bb.x; v[1] += bb.y; v[2] += bb.z; v[3] += bb.w;
        uint2 o; o.x = pack2bf(v[0], v[1]); o.y = pack2bf(v[2], v[3]);
        *reinterpret_cast<uint2*>(outb0 + idx) = o;
        float4 rl = {relu(v[0]), relu(v[1]), relu(v[2]), relu(v[3])};
        *reinterpret_cast<float4*>(outf + idx) = rl;
      } else {
        const uint2 ab = *reinterpret_cast<const uint2*>(addb + idx);
        v[0] += bflo(ab.x); v[1] += bfhi(ab.x);
        v[2] += bflo(ab.y); v[3] += bfhi(ab.y);
        float4 rl = {relu(v[0]), relu(v[1]), relu(v[2]), relu(v[3])};
        *reinterpret_cast<float4*>(outf + idx) = rl;
      }
    }
  }
}

// W_h GEMM via MFMA linearity: M'[r] = relu(inp[r] + amsg[b2a[r]]@W^T
//                                           - M[b2revb[r]]@W^T).
// BM=32, 4 waves x (32 rows x 64-col band).  BOTH gathered A-tiles staged
// by pure global_load_lds with per-lane source rows (idx broadcast loads)
// and source-side XOR swizzle; two accumulators, subtract in epilogue.
__global__ __launch_bounds__(256, 4) void gemm_wh(
    const u16* __restrict__ amsg, const u16* __restrict__ M,
    const int* __restrict__ b2a, const int* __restrict__ b2revb,
    const u16* __restrict__ Bw, const u16* __restrict__ inp,
    u16* __restrict__ outM) {
  __shared__ u16 Aa[32 * 256];
  __shared__ u16 Am[32 * 256];

  const int tid = threadIdx.x;
  const int lane = tid & 63, wid = tid >> 6;
  const int wn = wid * 64;
  const int m0 = blockIdx.x * 32;
  const int lm = lane & 15, lg = lane >> 4;

#pragma unroll
  for (int p = 0; p < 4; ++p) {
    const int q = wid * 4 + p;
    const int chunk = q * 64 + lane;
    const int row = chunk >> 5, k8 = chunk & 31;
    const int soff = (k8 ^ (row & 7)) * 8;  // u16 offset within row
    const int r1 = b2a[m0 + row];
    async16(amsg + (size_t)r1 * 256 + soff, &Aa[q * 512]);
    const int r2 = b2revb[m0 + row];
    async16(M + (size_t)r2 * 256 + soff, &Am[q * 512]);
  }
  __syncthreads();

  f32x4 ac1[2][4], ac2[2][4];
#pragma unroll
  for (int i = 0; i < 2; ++i)
#pragma unroll
    for (int j = 0; j < 4; ++j) { ac1[i][j] = (f32x4)(0.f); ac2[i][j] = (f32x4)(0.f); }

#pragma unroll
  for (int kk = 0; kk < 8; ++kk) {
    const int phys = (kk * 4 + lg) ^ (lm & 7);  // (16+lm)&7 == lm&7
    bf16x8 aa0 = *reinterpret_cast<const bf16x8*>(&Aa[lm * 256 + phys * 8]);
    bf16x8 aa1 = *reinterpret_cast<const bf16x8*>(&Aa[(16 + lm) * 256 + phys * 8]);
    bf16x8 am0 = *reinterpret_cast<const bf16x8*>(&Am[lm * 256 + phys * 8]);
    bf16x8 am1 = *reinterpret_cast<const bf16x8*>(&Am[(16 + lm) * 256 + phys * 8]);
#pragma unroll
    for (int jw = 0; jw < 4; ++jw) {
      bf16x8 b = *reinterpret_cast<const bf16x8*>(
          Bw + (size_t)(wn + jw * 16 + lm) * 256 + kk * 32 + lg * 8);
      ac1[0][jw] = __builtin_amdgcn_mfma_f32_16x16x32_bf16(b, aa0, ac1[0][jw], 0, 0, 0);
      ac1[1][jw] = __builtin_amdgcn_mfma_f32_16x16x32_bf16(b, aa1, ac1[1][jw], 0, 0, 0);
      ac2[0][jw] = __builtin_amdgcn_mfma_f32_16x16x32_bf16(b, am0, ac2[0][jw], 0, 0, 0);
      ac2[1][jw] = __builtin_amdgcn_mfma_f32_16x16x32_bf16(b, am1, ac2[1][jw], 0, 0, 0);
    }
  }

#pragma unroll
  for (int im = 0; im < 2; ++im) {
#pragma unroll
    for (int jw = 0; jw < 4; ++jw) {
      const int r = m0 + im * 16 + lm;
      const int c0 = wn + jw * 16 + lg * 4;
      const size_t idx = (size_t)r * 256 + c0;
      const uint2 ab = *reinterpret_cast<const uint2*>(inp + idx);
      float v0 = ac1[im][jw][0] - ac2[im][jw][0] + bflo(ab.x);
      float v1 = ac1[im][jw][1] - ac2[im][jw][1] + bfhi(ab.x);
      float v2 = ac1[im][jw][2] - ac2[im][jw][2] + bflo(ab.y);
      float v3 = ac1[im][jw][3] - ac2[im][jw][3] + bfhi(ab.y);
      uint2 o;
      o.x = pack2bf(relu(v0), relu(v1));
      o.y = pack2bf(relu(v2), relu(v3));
      *reinterpret_cast<uint2*>(outM + idx) = o;
    }
  }
}

// amsg[a][:] = sum_j M[a2b[a][j]][:]   (M is post-activation; pure sum)
__global__ __launch_bounds__(256) void gather_sum(const u16* __restrict__ M,
                                                  const int* __restrict__ a2b,
                                                  u16* __restrict__ amsg,
                                                  int n_atoms) {
  int wave = threadIdx.x >> 6, lane = threadIdx.x & 63;
  int atom = blockIdx.x * 4 + wave;
  if (atom >= n_atoms) return;
  float s0 = 0.f, s1 = 0.f, s2 = 0.f, s3 = 0.f;
  int base = atom * 6;
#pragma unroll
  for (int j = 0; j < 6; ++j) {
    int b = a2b[base + j];
    uint2 v = *reinterpret_cast<const uint2*>(M + (size_t)b * 256 + lane * 4);
    s0 += bflo(v.x); s1 += bfhi(v.x);
    s2 += bflo(v.y); s3 += bfhi(v.y);
  }
  uint2 o;
  o.x = pack2bf(s0, s1);
  o.y = pack2bf(s2, s3);
  *reinterpret_cast<uint2*>(amsg + (size_t)atom * 256 + lane * 4) = o;
}

__global__ __launch_bounds__(256) void mol_mean(const float* __restrict__ dfin,
                                                float* __restrict__ out) {
  int mol = blockIdx.x, c = threadIdx.x;
  const float* p = dfin + (size_t)mol * (42 * 256) + c;
  float s = 0.f;
#pragma unroll
  for (int a = 0; a < 42; ++a) s += p[a * 256];
  out[(size_t)mol * 256 + c] = s * (1.0f / 42.0f);
}

extern "C" void kernel_launch(void* const* d_in, const int* in_sizes, int n_in,
                              void* d_out, int out_size, void* d_ws,
                              size_t ws_size, hipStream_t stream) {
  const float* f_atoms = (const float*)d_in[0];
  const float* f_bonds = (const float*)d_in[1];
  const float* W_i = (const float*)d_in[2];
  const float* W_h = (const float*)d_in[3];
  const float* W_o = (const float*)d_in[4];
  const float* b_o = (const float*)d_in[5];
  const int* a2b = (const int*)d_in[6];
  const int* b2a = (const int*)d_in[7];
  const int* b2revb = (const int*)d_in[8];

  const int NA = 168000, NB = 360000, H = 256;
  const size_t SZ_BH = (size_t)NB * H * 2;   // 184.3 MB
  const size_t SZ_AH = (size_t)NA * H * 2;   //  86.0 MB

  char* ws = (char*)d_ws;
  u16* fb16  = (u16*)ws;  ws += (size_t)NB * 160 * 2;  // 115 MB
  u16* fa16  = (u16*)ws;  ws += (size_t)NA * 160 * 2;  //  54 MB
  u16* inp_b = (u16*)ws;  ws += SZ_BH;  // pre-act inp (W_h epilogue)
  u16* M0    = (u16*)ws;  ws += SZ_BH;  // post-act messages, depth 0
  u16* M1    = (u16*)ws;  ws += SZ_BH;
  u16* M2    = (u16*)ws;  ws += SZ_BH;
  u16* amsg  = (u16*)ws;  ws += SZ_AH;
  u16* base_b = (u16*)ws; ws += SZ_AH;
  u16* Wi_b  = (u16*)ws;  ws += 256 * 160 * 2;
  u16* Wh_b  = (u16*)ws;  ws += 256 * 256 * 2;
  u16* Wo1_b = (u16*)ws;  ws += 256 * 160 * 2;
  u16* Wo2_b = (u16*)ws;  ws += 256 * 256 * 2;

  float* out = (float*)d_out;
  float* d0 = out;
  float* d1 = d0 + (size_t)NA * H;
  float* d2 = d1 + (size_t)NA * H;
  float* dfin = d2 + (size_t)NA * H;
  float* mol = dfin + (size_t)NA * H;

  dim3 blk(256);
  cvt_all<<<dim3(832), blk, 0, stream>>>(W_i, W_h, W_o, Wi_b, Wh_b, Wo1_b, Wo2_b);
  cvt_feat<<<dim3((int)(((long)NB * 160 + 255) / 256)), blk, 0, stream>>>(
      f_bonds, fb16, 147, 160, (long)NB * 160);
  cvt_feat<<<dim3((int)(((long)NA * 160 + 255) / 256)), blk, 0, stream>>>(
      f_atoms, fa16, 133, 160, (long)NA * 160);

  // inp = f_bonds @ W_i^T ; M0 = relu(inp)
  gemm_async<160, 0><<<dim3(NB / 64), blk, 0, stream>>>(
      fb16, Wi_b, nullptr, nullptr, inp_b, M0, nullptr);
  // base = f_atoms @ W_o1^T + b_o (bf16) ; d0 = relu(base) f32
  gemm_async<160, 1><<<dim3(NA / 64), blk, 0, stream>>>(
      fa16, Wo1_b, nullptr, b_o, base_b, nullptr, d0);

  u16* Ms[3] = {M0, M1, M2};
  float* douts[3] = {d1, d2, dfin};
  for (int d = 0; d < 3; ++d) {
    gather_sum<<<dim3(NA / 4), blk, 0, stream>>>(Ms[d], a2b, amsg, NA);
    // d_{d+1} = relu(base + amsg @ W_o2^T)
    gemm_async<256, 3><<<dim3(NA / 64), blk, 0, stream>>>(
        amsg, Wo2_b, base_b, nullptr, nullptr, nullptr, douts[d]);
    if (d < 2) {
      // M_{d+1} = relu(inp + amsg[b2a]@W_h^T - M_d[b2revb]@W_h^T)
      gemm_wh<<<dim3(NB / 32), blk, 0, stream>>>(
          amsg, Ms[d], b2a, b2revb, Wh_b, inp_b, Ms[d + 1]);
    }
  }
  mol_mean<<<dim3(4000), blk, 0, stream>>>(dfin, mol);
}

// Round 13
// 1476.138 us; speedup vs baseline: 1.3411x; 1.1269x over previous
//
#include <hip/hip_runtime.h>

typedef unsigned short u16;
typedef unsigned int u32;
typedef __bf16 bf16x8 __attribute__((ext_vector_type(8)));
typedef float f32x4 __attribute__((ext_vector_type(4)));

__device__ __forceinline__ float bf2f(u16 h) {
  union { u32 u; float f; } c; c.u = ((u32)h) << 16; return c.f;
}
__device__ __forceinline__ float bflo(u32 u) {
  union { u32 u; float f; } c; c.u = u << 16; return c.f;
}
__device__ __forceinline__ float bfhi(u32 u) {
  union { u32 u; float f; } c; c.u = u & 0xffff0000u; return c.f;
}
// compiler emits packed v_cvt_pk_bf16_f32 for __bf16 casts (RNE)
__device__ __forceinline__ u32 pack2bf(float a, float b) {
  union { __bf16 h[2]; u32 u; } c; c.h[0] = (__bf16)a; c.h[1] = (__bf16)b;
  return c.u;
}
__device__ __forceinline__ u16 f2bf(float f) {
  union { __bf16 h; u16 u; } c; c.h = (__bf16)f; return c.u;
}
__device__ __forceinline__ float relu(float x) { return x > 0.f ? x : 0.f; }

// One-shot conversion of all four weight slices to bf16 [N][Kpad] layouts.
__global__ __launch_bounds__(256) void cvt_all(
    const float* __restrict__ Wi, const float* __restrict__ Wh,
    const float* __restrict__ Wo, u16* __restrict__ dWi, u16* __restrict__ dWh,
    u16* __restrict__ dWo1, u16* __restrict__ dWo2) {
  int i = blockIdx.x * 256 + threadIdx.x;
  if (i < 40960) {
    int n = i / 160, k = i % 160;
    dWi[i] = f2bf(k < 147 ? Wi[n * 147 + k] : 0.f);
  } else if (i < 106496) {
    int j = i - 40960;
    dWh[j] = f2bf(Wh[j]);
  } else if (i < 147456) {
    int j = i - 106496;
    int n = j / 160, k = j % 160;
    dWo1[j] = f2bf(k < 133 ? Wo[n * 389 + k] : 0.f);
  } else {
    int j = i - 147456;
    int n = j / 256, k = j % 256;
    dWo2[j] = f2bf(Wo[n * 389 + 133 + k]);
  }
}

// GEMM: C[M,256] = A[M,K] * W[256,K]^T.  BM=64, BN=256; 4 waves, each
// 64 rows x 64-col band.  A staged COALESCED into LDS once (1 barrier);
// B-fragments read from global (weights L2-resident, broadcast).
// Swapped-operand MFMA: acc = mfma(w_frag, a_frag) -> lane holds 4
// consecutive output columns (c0 = wn + jw*16 + (lane>>4)*4) at row
// m0 + im*16 + (lane&15).  Stores: bf16 = 8B uint2, f32 = 16B float4.
// Output must not alias any input (cross-wave WAR, round-4 lesson).
// No cross-phase staging registers (r3/r9 spill lesson).
// ASRC: 0 = A from f32 global [M][Kreal] (k<Kreal guard, converted)
//       2 = A row r = bf16( Ab[idx1[r]] - relu(Ab2[idx2[r]]) )  [KPAD=256]
//           (8 thr/row x 2 passes: peak 8 uint4 transient -> fits MINW=4,
//            matching the 33.8KB-LDS limit of 4 blocks/CU)
//       3 = A row r = bf16( sum_{j<6} relu(Ab[idx1[r*6+j]]) )   [KPAD=256]
//           (chunk-major: 6 neighbor loads issued together per chunk;
//            if WAMSG, staged rows also stored to amsg_out)
// EPI:  0 = bf16 acc -> outb0
//       1 = v=acc+bias[c]; bf16 v -> outb0; relu(v) f32 -> outf
//       2 = v=acc+bf2f(addb[idx]); bf16 v -> outb0   (pre-activation store)
//       3 = v=acc+bf2f(addb[idx]); relu(v) f32 -> outf
template <int ASRC, int EPI, int KPAD, int WAMSG, int MINW>
__global__ __launch_bounds__(256, MINW) void gemm13(
    const float* __restrict__ Af, int Kreal,
    const u16* __restrict__ Ab, const u16* __restrict__ Ab2,
    const int* __restrict__ idx1, const int* __restrict__ idx2,
    const u16* __restrict__ Bw,
    const u16* __restrict__ addb, const float* __restrict__ bias,
    u16* __restrict__ outb0, float* __restrict__ outf,
    u16* __restrict__ amsg_out) {
  constexpr int LDK = KPAD + 8;  // row stride 336/528B: 2-way bank alias, free
  __shared__ u16 As[64 * LDK];

  const int tid = threadIdx.x;
  const int lane = tid & 63;
  const int wn = (tid >> 6) * 64;
  const int m0 = blockIdx.x * 64;
  const int lm = lane & 15, lg = lane >> 4;
  const int koff = lg * 8;

  // ---- coalesced staging of A[64][KPAD] ----
  if constexpr (ASRC == 0) {
    // consecutive lanes -> consecutive k pairs (8B apart): coalesced dwords
#pragma unroll
    for (int p = 0; p < 64 * KPAD / 512; ++p) {
      int e = (p * 256 + tid) * 2;
      int row = e / KPAD, k = e % KPAD;
      const float* src = Af + (size_t)(m0 + row) * Kreal + k;
      float x0 = (k < Kreal) ? src[0] : 0.f;
      float x1 = (k + 1 < Kreal) ? src[1] : 0.f;
      *reinterpret_cast<u32*>(&As[row * LDK + k]) = pack2bf(x0, x1);
    }
  } else if constexpr (ASRC == 2) {
    // fused gather-subtract: 8 threads/row, 32-u16 (64B) segment, 2 passes
    static_assert(KPAD == 256, "ASRC2 assumes KPAD=256");
    const int row8 = tid >> 3, seg = tid & 7;
#pragma unroll
    for (int pass = 0; pass < 2; ++pass) {
      const int row = pass * 32 + row8;
      const int gr = m0 + row;
      const u16* pa = Ab + (size_t)idx1[gr] * 256 + seg * 32;
      const u16* pb = Ab2 + (size_t)idx2[gr] * 256 + seg * 32;
      uint4 va[4], vb[4];
#pragma unroll
      for (int i = 0; i < 4; ++i) {
        va[i] = *reinterpret_cast<const uint4*>(pa + i * 8);
        vb[i] = *reinterpret_cast<const uint4*>(pb + i * 8);
      }
      u16* dst = &As[row * LDK + seg * 32];
#pragma unroll
      for (int i = 0; i < 4; ++i) {
        uint4 o;
        o.x = pack2bf(bflo(va[i].x) - relu(bflo(vb[i].x)),
                      bfhi(va[i].x) - relu(bfhi(vb[i].x)));
        o.y = pack2bf(bflo(va[i].y) - relu(bflo(vb[i].y)),
                      bfhi(va[i].y) - relu(bfhi(vb[i].y)));
        o.z = pack2bf(bflo(va[i].z) - relu(bflo(vb[i].z)),
                      bfhi(va[i].z) - relu(bfhi(vb[i].z)));
        o.w = pack2bf(bflo(va[i].w) - relu(bflo(vb[i].w)),
                      bfhi(va[i].w) - relu(bfhi(vb[i].w)));
        *reinterpret_cast<uint4*>(dst + i * 8) = o;
      }
    }
  } else {
    // fused gather_sum: 8 threads/row (32-u16 seg), 2 passes of 32 rows.
    // Per 8-elem chunk all 6 neighbor loads issued together (MLP).
    static_assert(KPAD == 256, "ASRC3 assumes KPAD=256");
#pragma unroll
    for (int pass = 0; pass < 2; ++pass) {
      const int row = pass * 32 + (tid >> 3);
      const int seg = tid & 7;
      const int gr = m0 + row;
      const int* nbp = idx1 + gr * 6;
      int nn[6];
#pragma unroll
      for (int j = 0; j < 6; ++j) nn[j] = nbp[j];
      const u16* base = Ab + seg * 32;
#pragma unroll
      for (int c = 0; c < 4; ++c) {
        const int off = c * 8;
        uint4 v[6];
#pragma unroll
        for (int j = 0; j < 6; ++j)
          v[j] = *reinterpret_cast<const uint4*>(base + (size_t)nn[j] * 256 + off);
        float s[8];
#pragma unroll
        for (int e = 0; e < 8; ++e) s[e] = 0.f;
#pragma unroll
        for (int j = 0; j < 6; ++j) {
          s[0] += relu(bflo(v[j].x)); s[1] += relu(bfhi(v[j].x));
          s[2] += relu(bflo(v[j].y)); s[3] += relu(bfhi(v[j].y));
          s[4] += relu(bflo(v[j].z)); s[5] += relu(bfhi(v[j].z));
          s[6] += relu(bflo(v[j].w)); s[7] += relu(bfhi(v[j].w));
        }
        uint4 o;
        o.x = pack2bf(s[0], s[1]); o.y = pack2bf(s[2], s[3]);
        o.z = pack2bf(s[4], s[5]); o.w = pack2bf(s[6], s[7]);
        *reinterpret_cast<uint4*>(&As[row * LDK + seg * 32 + off]) = o;
        if constexpr (WAMSG)
          *reinterpret_cast<uint4*>(amsg_out + (size_t)gr * 256 + seg * 32 + off) = o;
      }
    }
  }
  __syncthreads();

  f32x4 acc[4][4];
#pragma unroll
  for (int i = 0; i < 4; ++i)
#pragma unroll
    for (int j = 0; j < 4; ++j) acc[i][j] = (f32x4)(0.f);

#pragma unroll
  for (int kk = 0; kk < KPAD / 32; ++kk) {
    const int k0 = kk * 32 + koff;
    bf16x8 a[4];
#pragma unroll
    for (int im = 0; im < 4; ++im)
      a[im] = *reinterpret_cast<const bf16x8*>(&As[(im * 16 + lm) * LDK + k0]);
#pragma unroll
    for (int jw = 0; jw < 4; ++jw) {
      bf16x8 b = *reinterpret_cast<const bf16x8*>(
          Bw + (size_t)(wn + jw * 16 + lm) * KPAD + k0);
#pragma unroll
      for (int im = 0; im < 4; ++im)
        acc[im][jw] = __builtin_amdgcn_mfma_f32_16x16x32_bf16(b, a[im], acc[im][jw], 0, 0, 0);
    }
  }

#pragma unroll
  for (int im = 0; im < 4; ++im) {
#pragma unroll
    for (int jw = 0; jw < 4; ++jw) {
      const int r = m0 + im * 16 + lm;
      const int c0 = wn + jw * 16 + lg * 4;
      const size_t idx = (size_t)r * 256 + c0;
      f32x4 v = acc[im][jw];
      if constexpr (EPI == 0) {
        uint2 o; o.x = pack2bf(v[0], v[1]); o.y = pack2bf(v[2], v[3]);
        *reinterpret_cast<uint2*>(outb0 + idx) = o;
      } else if constexpr (EPI == 1) {
        const float4 bb = *reinterpret_cast<const float4*>(bias + c0);
        v[0] += bb.x; v[1] += bb.y; v[2] += bb.z; v[3] += bb.w;
        uint2 o; o.x = pack2bf(v[0], v[1]); o.y = pack2bf(v[2], v[3]);
        *reinterpret_cast<uint2*>(outb0 + idx) = o;
        float4 rl = {relu(v[0]), relu(v[1]), relu(v[2]), relu(v[3])};
        *reinterpret_cast<float4*>(outf + idx) = rl;
      } else if constexpr (EPI == 2) {
        const uint2 ab = *reinterpret_cast<const uint2*>(addb + idx);
        v[0] += bflo(ab.x); v[1] += bfhi(ab.x);
        v[2] += bflo(ab.y); v[3] += bfhi(ab.y);
        uint2 o; o.x = pack2bf(v[0], v[1]); o.y = pack2bf(v[2], v[3]);
        *reinterpret_cast<uint2*>(outb0 + idx) = o;
      } else {
        const uint2 ab = *reinterpret_cast<const uint2*>(addb + idx);
        v[0] += bflo(ab.x); v[1] += bfhi(ab.x);
        v[2] += bflo(ab.y); v[3] += bfhi(ab.y);
        float4 rl = {relu(v[0]), relu(v[1]), relu(v[2]), relu(v[3])};
        *reinterpret_cast<float4*>(outf + idx) = rl;
      }
    }
  }
}

__global__ __launch_bounds__(256) void mol_mean(const float* __restrict__ dfin,
                                                float* __restrict__ out) {
  int mol = blockIdx.x, c = threadIdx.x;
  const float* p = dfin + (size_t)mol * (42 * 256) + c;
  float s = 0.f;
#pragma unroll
  for (int a = 0; a < 42; ++a) s += p[a * 256];
  out[(size_t)mol * 256 + c] = s * (1.0f / 42.0f);
}

extern "C" void kernel_launch(void* const* d_in, const int* in_sizes, int n_in,
                              void* d_out, int out_size, void* d_ws,
                              size_t ws_size, hipStream_t stream) {
  const float* f_atoms = (const float*)d_in[0];
  const float* f_bonds = (const float*)d_in[1];
  const float* W_i = (const float*)d_in[2];
  const float* W_h = (const float*)d_in[3];
  const float* W_o = (const float*)d_in[4];
  const float* b_o = (const float*)d_in[5];
  const int* a2b = (const int*)d_in[6];
  const int* b2a = (const int*)d_in[7];
  const int* b2revb = (const int*)d_in[8];

  const int NA = 168000, NB = 360000, H = 256;
  const size_t SZ_BH = (size_t)NB * H * 2;
  const size_t SZ_AH = (size_t)NA * H * 2;

  char* ws = (char*)d_ws;
  u16* inp_b = (u16*)ws;  ws += SZ_BH;   // S_0 (pre-act bond state = inp)
  u16* P0    = (u16*)ws;  ws += SZ_BH;   // S_1
  u16* P1    = (u16*)ws;  ws += SZ_BH;   // S_2
  u16* amsg  = (u16*)ws;  ws += SZ_AH;
  u16* base_b = (u16*)ws; ws += SZ_AH;
  u16* Wi_b  = (u16*)ws;  ws += 256 * 160 * 2;
  u16* Wh_b  = (u16*)ws;  ws += 256 * 256 * 2;
  u16* Wo1_b = (u16*)ws;  ws += 256 * 160 * 2;
  u16* Wo2_b = (u16*)ws;  ws += 256 * 256 * 2;

  float* out = (float*)d_out;
  float* d0 = out;
  float* d1 = d0 + (size_t)NA * H;
  float* d2 = d1 + (size_t)NA * H;
  float* dfin = d2 + (size_t)NA * H;
  float* mol = dfin + (size_t)NA * H;

  dim3 blk(256);
  cvt_all<<<dim3(832), blk, 0, stream>>>(W_i, W_h, W_o, Wi_b, Wh_b, Wo1_b, Wo2_b);

  // inp = f_bonds @ W_i^T  (pre-activation; relu fused into consumers)
  gemm13<0, 0, 160, 0, 4><<<dim3(NB / 64), blk, 0, stream>>>(
      f_bonds, 147, nullptr, nullptr, nullptr, nullptr, Wi_b,
      nullptr, nullptr, inp_b, nullptr, nullptr);
  // base = f_atoms @ W_o1^T + b_o (pre-relu, bf16) ; d0 = relu(base) f32
  gemm13<0, 1, 160, 0, 4><<<dim3(NA / 64), blk, 0, stream>>>(
      f_atoms, 133, nullptr, nullptr, nullptr, nullptr, Wo1_b,
      nullptr, b_o, base_b, d0, nullptr);

  u16* S = inp_b;
  u16* pms[2] = {P0, P1};
  float* douts[3] = {d1, d2, dfin};
  for (int d = 0; d < 3; ++d) {
    if (d < 2) {
      // d_{d+1} = relu(base + (gather-sum) @ W_o2^T); amsg written as side-out
      gemm13<3, 3, 256, 1, 4><<<dim3(NA / 64), blk, 0, stream>>>(
          nullptr, 0, S, nullptr, a2b, nullptr, Wo2_b,
          base_b, nullptr, nullptr, douts[d], amsg);
      // S' = inp + (amsg[b2a] - relu(S[b2revb])) @ W_h^T  (gather fused)
      gemm13<2, 2, 256, 0, 4><<<dim3(NB / 64), blk, 0, stream>>>(
          nullptr, 0, amsg, S, b2a, b2revb, Wh_b,
          inp_b, nullptr, pms[d], nullptr, nullptr);
      S = pms[d];
    } else {
      gemm13<3, 3, 256, 0, 4><<<dim3(NA / 64), blk, 0, stream>>>(
          nullptr, 0, S, nullptr, a2b, nullptr, Wo2_b,
          base_b, nullptr, nullptr, douts[d], nullptr);
    }
  }
  mol_mean<<<dim3(4000), blk, 0, stream>>>(dfin, mol);
}

// Round 14
// 1449.405 us; speedup vs baseline: 1.3659x; 1.0184x over previous
//
#include <hip/hip_runtime.h>

typedef unsigned short u16;
typedef unsigned int u32;
typedef __bf16 bf16x8 __attribute__((ext_vector_type(8)));
typedef float f32x4 __attribute__((ext_vector_type(4)));

__device__ __forceinline__ float bf2f(u16 h) {
  union { u32 u; float f; } c; c.u = ((u32)h) << 16; return c.f;
}
__device__ __forceinline__ float bflo(u32 u) {
  union { u32 u; float f; } c; c.u = u << 16; return c.f;
}
__device__ __forceinline__ float bfhi(u32 u) {
  union { u32 u; float f; } c; c.u = u & 0xffff0000u; return c.f;
}
// compiler emits packed v_cvt_pk_bf16_f32 for __bf16 casts (RNE)
__device__ __forceinline__ u32 pack2bf(float a, float b) {
  union { __bf16 h[2]; u32 u; } c; c.h[0] = (__bf16)a; c.h[1] = (__bf16)b;
  return c.u;
}
__device__ __forceinline__ u16 f2bf(float f) {
  union { __bf16 h; u16 u; } c; c.h = (__bf16)f; return c.u;
}
__device__ __forceinline__ float relu(float x) { return x > 0.f ? x : 0.f; }
// non-temporal f32x4 store: depth outputs are write-once/never-re-read;
// nt keeps them from evicting the gather working set out of L3.
__device__ __forceinline__ void nt_store4(float* p, float a, float b, float c,
                                          float d) {
  f32x4 v = {a, b, c, d};
  __builtin_nontemporal_store(v, reinterpret_cast<f32x4*>(p));
}

// One-shot conversion of all four weight slices to bf16 [N][Kpad] layouts.
__global__ __launch_bounds__(256) void cvt_all(
    const float* __restrict__ Wi, const float* __restrict__ Wh,
    const float* __restrict__ Wo, u16* __restrict__ dWi, u16* __restrict__ dWh,
    u16* __restrict__ dWo1, u16* __restrict__ dWo2) {
  int i = blockIdx.x * 256 + threadIdx.x;
  if (i < 40960) {
    int n = i / 160, k = i % 160;
    dWi[i] = f2bf(k < 147 ? Wi[n * 147 + k] : 0.f);
  } else if (i < 106496) {
    int j = i - 40960;
    dWh[j] = f2bf(Wh[j]);
  } else if (i < 147456) {
    int j = i - 106496;
    int n = j / 160, k = j % 160;
    dWo1[j] = f2bf(k < 133 ? Wo[n * 389 + k] : 0.f);
  } else {
    int j = i - 147456;
    int n = j / 256, k = j % 256;
    dWo2[j] = f2bf(Wo[n * 389 + 133 + k]);
  }
}

// GEMM: C[M,256] = A[M,K] * W[256,K]^T.  BM=64, BN=256; 4 waves, each
// 64 rows x 64-col band.  A staged COALESCED into LDS once (1 barrier);
// B-fragments read from global (weights L2-resident, broadcast).
// Swapped-operand MFMA: acc = mfma(w_frag, a_frag) -> lane holds 4
// consecutive output columns (c0 = wn + jw*16 + (lane>>4)*4) at row
// m0 + im*16 + (lane&15).  Stores: bf16 = 8B uint2, f32 = 16B (nt where
// write-once).  Output must not alias any input (cross-wave WAR, r4 lesson).
// No cross-phase staging registers (r3/r9 spill lesson).
// ASRC: 0 = A from f32 global [M][Kreal] (k<Kreal guard, converted)
//       2 = A row r = bf16( Ab[idx1[r]] - relu(Ab2[idx2[r]]) )  [KPAD=256]
//       3 = A row r = bf16( sum_{j<6} relu(Ab[idx1[r*6+j]]) )   [KPAD=256]
//           (chunk-major, 6 neighbor loads issued together; MINW=3 gives
//            VGPR headroom for the 24-deep load burst)
// EPI:  0 = bf16 acc -> outb0
//       1 = v=acc+bias[c]; bf16 v -> outb0; relu(v) f32 nt -> outf
//       2 = v=acc+bf2f(addb[idx]); bf16 v -> outb0   (pre-activation store)
//       3 = v=acc+bf2f(addb[idx]); relu(v) f32 nt -> outf
template <int ASRC, int EPI, int KPAD, int WAMSG, int MINW>
__global__ __launch_bounds__(256, MINW) void gemm14(
    const float* __restrict__ Af, int Kreal,
    const u16* __restrict__ Ab, const u16* __restrict__ Ab2,
    const int* __restrict__ idx1, const int* __restrict__ idx2,
    const u16* __restrict__ Bw,
    const u16* __restrict__ addb, const float* __restrict__ bias,
    u16* __restrict__ outb0, float* __restrict__ outf,
    u16* __restrict__ amsg_out) {
  constexpr int LDK = KPAD + 8;  // row stride 336/528B: 2-way bank alias, free
  __shared__ u16 As[64 * LDK];

  const int tid = threadIdx.x;
  const int lane = tid & 63;
  const int wn = (tid >> 6) * 64;
  const int m0 = blockIdx.x * 64;
  const int lm = lane & 15, lg = lane >> 4;
  const int koff = lg * 8;

  // ---- coalesced staging of A[64][KPAD] ----
  if constexpr (ASRC == 0) {
#pragma unroll
    for (int p = 0; p < 64 * KPAD / 512; ++p) {
      int e = (p * 256 + tid) * 2;
      int row = e / KPAD, k = e % KPAD;
      const float* src = Af + (size_t)(m0 + row) * Kreal + k;
      float x0 = (k < Kreal) ? src[0] : 0.f;
      float x1 = (k + 1 < Kreal) ? src[1] : 0.f;
      *reinterpret_cast<u32*>(&As[row * LDK + k]) = pack2bf(x0, x1);
    }
  } else if constexpr (ASRC == 2) {
    // fused gather-subtract: 8 threads/row, 32-u16 (64B) segment, 2 passes
    static_assert(KPAD == 256, "ASRC2 assumes KPAD=256");
    const int row8 = tid >> 3, seg = tid & 7;
#pragma unroll
    for (int pass = 0; pass < 2; ++pass) {
      const int row = pass * 32 + row8;
      const int gr = m0 + row;
      const u16* pa = Ab + (size_t)idx1[gr] * 256 + seg * 32;
      const u16* pb = Ab2 + (size_t)idx2[gr] * 256 + seg * 32;
      uint4 va[4], vb[4];
#pragma unroll
      for (int i = 0; i < 4; ++i) {
        va[i] = *reinterpret_cast<const uint4*>(pa + i * 8);
        vb[i] = *reinterpret_cast<const uint4*>(pb + i * 8);
      }
      u16* dst = &As[row * LDK + seg * 32];
#pragma unroll
      for (int i = 0; i < 4; ++i) {
        uint4 o;
        o.x = pack2bf(bflo(va[i].x) - relu(bflo(vb[i].x)),
                      bfhi(va[i].x) - relu(bfhi(vb[i].x)));
        o.y = pack2bf(bflo(va[i].y) - relu(bflo(vb[i].y)),
                      bfhi(va[i].y) - relu(bfhi(vb[i].y)));
        o.z = pack2bf(bflo(va[i].z) - relu(bflo(vb[i].z)),
                      bfhi(va[i].z) - relu(bfhi(vb[i].z)));
        o.w = pack2bf(bflo(va[i].w) - relu(bflo(vb[i].w)),
                      bfhi(va[i].w) - relu(bfhi(vb[i].w)));
        *reinterpret_cast<uint4*>(dst + i * 8) = o;
      }
    }
  } else {
    // fused gather_sum: 8 threads/row (32-u16 seg), 2 passes of 32 rows.
    static_assert(KPAD == 256, "ASRC3 assumes KPAD=256");
#pragma unroll
    for (int pass = 0; pass < 2; ++pass) {
      const int row = pass * 32 + (tid >> 3);
      const int seg = tid & 7;
      const int gr = m0 + row;
      const int* nbp = idx1 + gr * 6;
      int nn[6];
#pragma unroll
      for (int j = 0; j < 6; ++j) nn[j] = nbp[j];
      const u16* base = Ab + seg * 32;
#pragma unroll
      for (int c = 0; c < 4; ++c) {
        const int off = c * 8;
        uint4 v[6];
#pragma unroll
        for (int j = 0; j < 6; ++j)
          v[j] = *reinterpret_cast<const uint4*>(base + (size_t)nn[j] * 256 + off);
        float s[8];
#pragma unroll
        for (int e = 0; e < 8; ++e) s[e] = 0.f;
#pragma unroll
        for (int j = 0; j < 6; ++j) {
          s[0] += relu(bflo(v[j].x)); s[1] += relu(bfhi(v[j].x));
          s[2] += relu(bflo(v[j].y)); s[3] += relu(bfhi(v[j].y));
          s[4] += relu(bflo(v[j].z)); s[5] += relu(bfhi(v[j].z));
          s[6] += relu(bflo(v[j].w)); s[7] += relu(bfhi(v[j].w));
        }
        uint4 o;
        o.x = pack2bf(s[0], s[1]); o.y = pack2bf(s[2], s[3]);
        o.z = pack2bf(s[4], s[5]); o.w = pack2bf(s[6], s[7]);
        *reinterpret_cast<uint4*>(&As[row * LDK + seg * 32 + off]) = o;
        if constexpr (WAMSG)
          *reinterpret_cast<uint4*>(amsg_out + (size_t)gr * 256 + seg * 32 + off) = o;
      }
    }
  }
  __syncthreads();

  f32x4 acc[4][4];
#pragma unroll
  for (int i = 0; i < 4; ++i)
#pragma unroll
    for (int j = 0; j < 4; ++j) acc[i][j] = (f32x4)(0.f);

#pragma unroll
  for (int kk = 0; kk < KPAD / 32; ++kk) {
    const int k0 = kk * 32 + koff;
    bf16x8 a[4];
#pragma unroll
    for (int im = 0; im < 4; ++im)
      a[im] = *reinterpret_cast<const bf16x8*>(&As[(im * 16 + lm) * LDK + k0]);
#pragma unroll
    for (int jw = 0; jw < 4; ++jw) {
      bf16x8 b = *reinterpret_cast<const bf16x8*>(
          Bw + (size_t)(wn + jw * 16 + lm) * KPAD + k0);
#pragma unroll
      for (int im = 0; im < 4; ++im)
        acc[im][jw] = __builtin_amdgcn_mfma_f32_16x16x32_bf16(b, a[im], acc[im][jw], 0, 0, 0);
    }
  }

#pragma unroll
  for (int im = 0; im < 4; ++im) {
#pragma unroll
    for (int jw = 0; jw < 4; ++jw) {
      const int r = m0 + im * 16 + lm;
      const int c0 = wn + jw * 16 + lg * 4;
      const size_t idx = (size_t)r * 256 + c0;
      f32x4 v = acc[im][jw];
      if constexpr (EPI == 0) {
        uint2 o; o.x = pack2bf(v[0], v[1]); o.y = pack2bf(v[2], v[3]);
        *reinterpret_cast<uint2*>(outb0 + idx) = o;
      } else if constexpr (EPI == 1) {
        const float4 bb = *reinterpret_cast<const float4*>(bias + c0);
        v[0] += bb.x; v[1] += bb.y; v[2] += bb.z; v[3] += bb.w;
        uint2 o; o.x = pack2bf(v[0], v[1]); o.y = pack2bf(v[2], v[3]);
        *reinterpret_cast<uint2*>(outb0 + idx) = o;
        nt_store4(outf + idx, relu(v[0]), relu(v[1]), relu(v[2]), relu(v[3]));
      } else if constexpr (EPI == 2) {
        const uint2 ab = *reinterpret_cast<const uint2*>(addb + idx);
        v[0] += bflo(ab.x); v[1] += bfhi(ab.x);
        v[2] += bflo(ab.y); v[3] += bfhi(ab.y);
        uint2 o; o.x = pack2bf(v[0], v[1]); o.y = pack2bf(v[2], v[3]);
        *reinterpret_cast<uint2*>(outb0 + idx) = o;
      } else {
        const uint2 ab = *reinterpret_cast<const uint2*>(addb + idx);
        v[0] += bflo(ab.x); v[1] += bfhi(ab.x);
        v[2] += bflo(ab.y); v[3] += bfhi(ab.y);
        nt_store4(outf + idx, relu(v[0]), relu(v[1]), relu(v[2]), relu(v[3]));
      }
    }
  }
}

__global__ __launch_bounds__(256) void mol_mean(const float* __restrict__ dfin,
                                                float* __restrict__ out) {
  int mol = blockIdx.x, c = threadIdx.x;
  const float* p = dfin + (size_t)mol * (42 * 256) + c;
  float s = 0.f;
#pragma unroll
  for (int a = 0; a < 42; ++a) s += p[a * 256];
  out[(size_t)mol * 256 + c] = s * (1.0f / 42.0f);
}

extern "C" void kernel_launch(void* const* d_in, const int* in_sizes, int n_in,
                              void* d_out, int out_size, void* d_ws,
                              size_t ws_size, hipStream_t stream) {
  const float* f_atoms = (const float*)d_in[0];
  const float* f_bonds = (const float*)d_in[1];
  const float* W_i = (const float*)d_in[2];
  const float* W_h = (const float*)d_in[3];
  const float* W_o = (const float*)d_in[4];
  const float* b_o = (const float*)d_in[5];
  const int* a2b = (const int*)d_in[6];
  const int* b2a = (const int*)d_in[7];
  const int* b2revb = (const int*)d_in[8];

  const int NA = 168000, NB = 360000, H = 256;
  const size_t SZ_BH = (size_t)NB * H * 2;
  const size_t SZ_AH = (size_t)NA * H * 2;

  char* ws = (char*)d_ws;
  u16* inp_b = (u16*)ws;  ws += SZ_BH;   // S_0 (pre-act bond state = inp)
  u16* P0    = (u16*)ws;  ws += SZ_BH;   // S_1
  u16* P1    = (u16*)ws;  ws += SZ_BH;   // S_2
  u16* amsg  = (u16*)ws;  ws += SZ_AH;
  u16* base_b = (u16*)ws; ws += SZ_AH;
  u16* Wi_b  = (u16*)ws;  ws += 256 * 160 * 2;
  u16* Wh_b  = (u16*)ws;  ws += 256 * 256 * 2;
  u16* Wo1_b = (u16*)ws;  ws += 256 * 160 * 2;
  u16* Wo2_b = (u16*)ws;  ws += 256 * 256 * 2;

  float* out = (float*)d_out;
  float* d0 = out;
  float* d1 = d0 + (size_t)NA * H;
  float* d2 = d1 + (size_t)NA * H;
  float* dfin = d2 + (size_t)NA * H;
  float* mol = dfin + (size_t)NA * H;

  dim3 blk(256);
  cvt_all<<<dim3(832), blk, 0, stream>>>(W_i, W_h, W_o, Wi_b, Wh_b, Wo1_b, Wo2_b);

  // inp = f_bonds @ W_i^T  (pre-activation; relu fused into consumers)
  gemm14<0, 0, 160, 0, 4><<<dim3(NB / 64), blk, 0, stream>>>(
      f_bonds, 147, nullptr, nullptr, nullptr, nullptr, Wi_b,
      nullptr, nullptr, inp_b, nullptr, nullptr);
  // base = f_atoms @ W_o1^T + b_o (pre-relu, bf16) ; d0 = relu(base) f32 nt
  gemm14<0, 1, 160, 0, 4><<<dim3(NA / 64), blk, 0, stream>>>(
      f_atoms, 133, nullptr, nullptr, nullptr, nullptr, Wo1_b,
      nullptr, b_o, base_b, d0, nullptr);

  u16* S = inp_b;
  u16* pms[2] = {P0, P1};
  float* douts[3] = {d1, d2, dfin};
  for (int d = 0; d < 3; ++d) {
    if (d < 2) {
      // d_{d+1} = relu(base + (gather-sum) @ W_o2^T); amsg written as side-out
      gemm14<3, 3, 256, 1, 3><<<dim3(NA / 64), blk, 0, stream>>>(
          nullptr, 0, S, nullptr, a2b, nullptr, Wo2_b,
          base_b, nullptr, nullptr, douts[d], amsg);
      // S' = inp + (amsg[b2a] - relu(S[b2revb])) @ W_h^T  (gather fused)
      gemm14<2, 2, 256, 0, 4><<<dim3(NB / 64), blk, 0, stream>>>(
          nullptr, 0, amsg, S, b2a, b2revb, Wh_b,
          inp_b, nullptr, pms[d], nullptr, nullptr);
      S = pms[d];
    } else {
      gemm14<3, 3, 256, 0, 3><<<dim3(NA / 64), blk, 0, stream>>>(
          nullptr, 0, S, nullptr, a2b, nullptr, Wo2_b,
          base_b, nullptr, nullptr, douts[d], nullptr);
    }
  }
  mol_mean<<<dim3(4000), blk, 0, stream>>>(dfin, mol);
}

// Round 15
// 1409.475 us; speedup vs baseline: 1.4046x; 1.0283x over previous
//
#include <hip/hip_runtime.h>

typedef unsigned short u16;
typedef unsigned int u32;
typedef __bf16 bf16x8 __attribute__((ext_vector_type(8)));
typedef float f32x4 __attribute__((ext_vector_type(4)));

__device__ __forceinline__ float bf2f(u16 h) {
  union { u32 u; float f; } c; c.u = ((u32)h) << 16; return c.f;
}
__device__ __forceinline__ float bflo(u32 u) {
  union { u32 u; float f; } c; c.u = u << 16; return c.f;
}
__device__ __forceinline__ float bfhi(u32 u) {
  union { u32 u; float f; } c; c.u = u & 0xffff0000u; return c.f;
}
// compiler emits packed v_cvt_pk_bf16_f32 for __bf16 casts (RNE)
__device__ __forceinline__ u32 pack2bf(float a, float b) {
  union { __bf16 h[2]; u32 u; } c; c.h[0] = (__bf16)a; c.h[1] = (__bf16)b;
  return c.u;
}
__device__ __forceinline__ u16 f2bf(float f) {
  union { __bf16 h; u16 u; } c; c.h = (__bf16)f; return c.u;
}
__device__ __forceinline__ float relu(float x) { return x > 0.f ? x : 0.f; }
// non-temporal f32x4 store: depth outputs are write-once/never-re-read.
__device__ __forceinline__ void nt_store4(float* p, float a, float b, float c,
                                          float d) {
  f32x4 v = {a, b, c, d};
  __builtin_nontemporal_store(v, reinterpret_cast<f32x4*>(p));
}

// One-shot conversion of all four weight slices to bf16 [N][Kpad] layouts.
__global__ __launch_bounds__(256) void cvt_all(
    const float* __restrict__ Wi, const float* __restrict__ Wh,
    const float* __restrict__ Wo, u16* __restrict__ dWi, u16* __restrict__ dWh,
    u16* __restrict__ dWo1, u16* __restrict__ dWo2) {
  int i = blockIdx.x * 256 + threadIdx.x;
  if (i < 40960) {
    int n = i / 160, k = i % 160;
    dWi[i] = f2bf(k < 147 ? Wi[n * 147 + k] : 0.f);
  } else if (i < 106496) {
    int j = i - 40960;
    dWh[j] = f2bf(Wh[j]);
  } else if (i < 147456) {
    int j = i - 106496;
    int n = j / 160, k = j % 160;
    dWo1[j] = f2bf(k < 133 ? Wo[n * 389 + k] : 0.f);
  } else {
    int j = i - 147456;
    int n = j / 256, k = j % 256;
    dWo2[j] = f2bf(Wo[n * 389 + 133 + k]);
  }
}

// GEMM: C[M,256] = A[M,K] * W[256,K]^T.  BM=64, BN=256; 4 waves, each
// 64 rows x 64-col band.  A staged into LDS once (1 barrier); B-fragments
// read from global (weights L2-resident, broadcast).
// Gather staging is ROW-MAJOR WAVE-PER-ROW: wave w owns rows w*16..w*16+15;
// per row all 64 lanes read 8B at lane*8 -> each VMEM instruction covers ONE
// contiguous 512B row (lane-merged line requests) instead of 64 scattered
// 16B pieces (the r7-r13 layout).  Row indices are wave-uniform -> scalar
// loads.  Theory: TA/TCP line-request rate, not data BW, capped gathers.
// Swapped-operand MFMA epilogue: lane holds 4 consecutive output columns
// (c0 = wn + jw*16 + (lane>>4)*4) at row m0 + im*16 + (lane&15).
// Stores: bf16 = 8B uint2, f32 = 16B nt.  Output must not alias any input
// (cross-wave WAR, r4 lesson).  No cross-phase staging regs (r3/r9 lesson).
// ASRC: 0 = A from f32 global [M][Kreal] (k<Kreal guard, converted)
//       2 = A row r = bf16( Ab[idx1[r]] - relu(Ab2[idx2[r]]) )  [KPAD=256]
//       3 = A row r = bf16( sum_{j<6} relu(Ab[idx1[r*6+j]]) )   [KPAD=256]
//           (if WAMSG, staged rows also stored to amsg_out, coalesced)
// EPI:  0 = bf16 acc -> outb0
//       1 = v=acc+bias[c]; bf16 v -> outb0; relu(v) f32 nt -> outf
//       2 = v=acc+bf2f(addb[idx]); bf16 v -> outb0   (pre-activation store)
//       3 = v=acc+bf2f(addb[idx]); relu(v) f32 nt -> outf
template <int ASRC, int EPI, int KPAD, int WAMSG, int MINW>
__global__ __launch_bounds__(256, MINW) void gemm15(
    const float* __restrict__ Af, int Kreal,
    const u16* __restrict__ Ab, const u16* __restrict__ Ab2,
    const int* __restrict__ idx1, const int* __restrict__ idx2,
    const u16* __restrict__ Bw,
    const u16* __restrict__ addb, const float* __restrict__ bias,
    u16* __restrict__ outb0, float* __restrict__ outf,
    u16* __restrict__ amsg_out) {
  constexpr int LDK = KPAD + 8;  // row stride 336/528B: 2-way bank alias, free
  __shared__ u16 As[64 * LDK];

  const int tid = threadIdx.x;
  const int lane = tid & 63;
  const int wn = (tid >> 6) * 64;
  const int m0 = blockIdx.x * 64;
  const int lm = lane & 15, lg = lane >> 4;
  const int koff = lg * 8;

  // ---- staging of A[64][KPAD] ----
  if constexpr (ASRC == 0) {
    // consecutive lanes -> consecutive k pairs: coalesced dword loads
#pragma unroll
    for (int p = 0; p < 64 * KPAD / 512; ++p) {
      int e = (p * 256 + tid) * 2;
      int row = e / KPAD, k = e % KPAD;
      const float* src = Af + (size_t)(m0 + row) * Kreal + k;
      float x0 = (k < Kreal) ? src[0] : 0.f;
      float x1 = (k + 1 < Kreal) ? src[1] : 0.f;
      *reinterpret_cast<u32*>(&As[row * LDK + k]) = pack2bf(x0, x1);
    }
  } else if constexpr (ASRC == 2) {
    // fused gather-subtract, wave-per-row: 2 contiguous 512B row reads/row
    static_assert(KPAD == 256, "ASRC2 assumes KPAD=256");
    const int wrow0 = (tid >> 6) * 16;
    const int l8 = lane * 4;  // u16 offset: lane*8 bytes
#pragma unroll 4
    for (int rr = 0; rr < 16; ++rr) {
      const int row = wrow0 + rr;
      const int gr = m0 + row;
      const int r1 = idx1[gr], r2 = idx2[gr];  // wave-uniform -> scalar
      uint2 va = *reinterpret_cast<const uint2*>(Ab + (size_t)r1 * 256 + l8);
      uint2 vb = *reinterpret_cast<const uint2*>(Ab2 + (size_t)r2 * 256 + l8);
      uint2 o;
      o.x = pack2bf(bflo(va.x) - relu(bflo(vb.x)),
                    bfhi(va.x) - relu(bfhi(vb.x)));
      o.y = pack2bf(bflo(va.y) - relu(bflo(vb.y)),
                    bfhi(va.y) - relu(bfhi(vb.y)));
      *reinterpret_cast<uint2*>(&As[row * LDK + l8]) = o;
    }
  } else {
    // fused gather_sum, wave-per-row: 6 contiguous 512B row reads per row,
    // issued together; accumulate in regs; 8B/lane LDS + amsg writes.
    static_assert(KPAD == 256, "ASRC3 assumes KPAD=256");
    const int wrow0 = (tid >> 6) * 16;
    const int l8 = lane * 4;
#pragma unroll 2
    for (int rr = 0; rr < 16; ++rr) {
      const int row = wrow0 + rr;
      const int gr = m0 + row;
      const int* nbp = idx1 + gr * 6;  // wave-uniform -> scalar loads
      uint2 v[6];
#pragma unroll
      for (int j = 0; j < 6; ++j)
        v[j] = *reinterpret_cast<const uint2*>(Ab + (size_t)nbp[j] * 256 + l8);
      float s0 = 0.f, s1 = 0.f, s2 = 0.f, s3 = 0.f;
#pragma unroll
      for (int j = 0; j < 6; ++j) {
        s0 += relu(bflo(v[j].x)); s1 += relu(bfhi(v[j].x));
        s2 += relu(bflo(v[j].y)); s3 += relu(bfhi(v[j].y));
      }
      uint2 o;
      o.x = pack2bf(s0, s1);
      o.y = pack2bf(s2, s3);
      *reinterpret_cast<uint2*>(&As[row * LDK + l8]) = o;
      if constexpr (WAMSG)
        *reinterpret_cast<uint2*>(amsg_out + (size_t)gr * 256 + l8) = o;
    }
  }
  __syncthreads();

  f32x4 acc[4][4];
#pragma unroll
  for (int i = 0; i < 4; ++i)
#pragma unroll
    for (int j = 0; j < 4; ++j) acc[i][j] = (f32x4)(0.f);

#pragma unroll
  for (int kk = 0; kk < KPAD / 32; ++kk) {
    const int k0 = kk * 32 + koff;
    bf16x8 a[4];
#pragma unroll
    for (int im = 0; im < 4; ++im)
      a[im] = *reinterpret_cast<const bf16x8*>(&As[(im * 16 + lm) * LDK + k0]);
#pragma unroll
    for (int jw = 0; jw < 4; ++jw) {
      bf16x8 b = *reinterpret_cast<const bf16x8*>(
          Bw + (size_t)(wn + jw * 16 + lm) * KPAD + k0);
#pragma unroll
      for (int im = 0; im < 4; ++im)
        acc[im][jw] = __builtin_amdgcn_mfma_f32_16x16x32_bf16(b, a[im], acc[im][jw], 0, 0, 0);
    }
  }

#pragma unroll
  for (int im = 0; im < 4; ++im) {
#pragma unroll
    for (int jw = 0; jw < 4; ++jw) {
      const int r = m0 + im * 16 + lm;
      const int c0 = wn + jw * 16 + lg * 4;
      const size_t idx = (size_t)r * 256 + c0;
      f32x4 v = acc[im][jw];
      if constexpr (EPI == 0) {
        uint2 o; o.x = pack2bf(v[0], v[1]); o.y = pack2bf(v[2], v[3]);
        *reinterpret_cast<uint2*>(outb0 + idx) = o;
      } else if constexpr (EPI == 1) {
        const float4 bb = *reinterpret_cast<const float4*>(bias + c0);
        v[0] += bb.x; v[1] += bb.y; v[2] += bb.z; v[3] += bb.w;
        uint2 o; o.x = pack2bf(v[0], v[1]); o.y = pack2bf(v[2], v[3]);
        *reinterpret_cast<uint2*>(outb0 + idx) = o;
        nt_store4(outf + idx, relu(v[0]), relu(v[1]), relu(v[2]), relu(v[3]));
      } else if constexpr (EPI == 2) {
        const uint2 ab = *reinterpret_cast<const uint2*>(addb + idx);
        v[0] += bflo(ab.x); v[1] += bfhi(ab.x);
        v[2] += bflo(ab.y); v[3] += bfhi(ab.y);
        uint2 o; o.x = pack2bf(v[0], v[1]); o.y = pack2bf(v[2], v[3]);
        *reinterpret_cast<uint2*>(outb0 + idx) = o;
      } else {
        const uint2 ab = *reinterpret_cast<const uint2*>(addb + idx);
        v[0] += bflo(ab.x); v[1] += bfhi(ab.x);
        v[2] += bflo(ab.y); v[3] += bfhi(ab.y);
        nt_store4(outf + idx, relu(v[0]), relu(v[1]), relu(v[2]), relu(v[3]));
      }
    }
  }
}

__global__ __launch_bounds__(256) void mol_mean(const float* __restrict__ dfin,
                                                float* __restrict__ out) {
  int mol = blockIdx.x, c = threadIdx.x;
  const float* p = dfin + (size_t)mol * (42 * 256) + c;
  float s = 0.f;
#pragma unroll
  for (int a = 0; a < 42; ++a) s += p[a * 256];
  out[(size_t)mol * 256 + c] = s * (1.0f / 42.0f);
}

extern "C" void kernel_launch(void* const* d_in, const int* in_sizes, int n_in,
                              void* d_out, int out_size, void* d_ws,
                              size_t ws_size, hipStream_t stream) {
  const float* f_atoms = (const float*)d_in[0];
  const float* f_bonds = (const float*)d_in[1];
  const float* W_i = (const float*)d_in[2];
  const float* W_h = (const float*)d_in[3];
  const float* W_o = (const float*)d_in[4];
  const float* b_o = (const float*)d_in[5];
  const int* a2b = (const int*)d_in[6];
  const int* b2a = (const int*)d_in[7];
  const int* b2revb = (const int*)d_in[8];

  const int NA = 168000, NB = 360000, H = 256;
  const size_t SZ_BH = (size_t)NB * H * 2;
  const size_t SZ_AH = (size_t)NA * H * 2;

  char* ws = (char*)d_ws;
  u16* inp_b = (u16*)ws;  ws += SZ_BH;   // S_0 (pre-act bond state = inp)
  u16* P0    = (u16*)ws;  ws += SZ_BH;   // S_1
  u16* P1    = (u16*)ws;  ws += SZ_BH;   // S_2
  u16* amsg  = (u16*)ws;  ws += SZ_AH;
  u16* base_b = (u16*)ws; ws += SZ_AH;
  u16* Wi_b  = (u16*)ws;  ws += 256 * 160 * 2;
  u16* Wh_b  = (u16*)ws;  ws += 256 * 256 * 2;
  u16* Wo1_b = (u16*)ws;  ws += 256 * 160 * 2;
  u16* Wo2_b = (u16*)ws;  ws += 256 * 256 * 2;

  float* out = (float*)d_out;
  float* d0 = out;
  float* d1 = d0 + (size_t)NA * H;
  float* d2 = d1 + (size_t)NA * H;
  float* dfin = d2 + (size_t)NA * H;
  float* mol = dfin + (size_t)NA * H;

  dim3 blk(256);
  cvt_all<<<dim3(832), blk, 0, stream>>>(W_i, W_h, W_o, Wi_b, Wh_b, Wo1_b, Wo2_b);

  // inp = f_bonds @ W_i^T  (pre-activation; relu fused into consumers)
  gemm15<0, 0, 160, 0, 4><<<dim3(NB / 64), blk, 0, stream>>>(
      f_bonds, 147, nullptr, nullptr, nullptr, nullptr, Wi_b,
      nullptr, nullptr, inp_b, nullptr, nullptr);
  // base = f_atoms @ W_o1^T + b_o (pre-relu, bf16) ; d0 = relu(base) f32 nt
  gemm15<0, 1, 160, 0, 4><<<dim3(NA / 64), blk, 0, stream>>>(
      f_atoms, 133, nullptr, nullptr, nullptr, nullptr, Wo1_b,
      nullptr, b_o, base_b, d0, nullptr);

  u16* S = inp_b;
  u16* pms[2] = {P0, P1};
  float* douts[3] = {d1, d2, dfin};
  for (int d = 0; d < 3; ++d) {
    if (d < 2) {
      // d_{d+1} = relu(base + (gather-sum) @ W_o2^T); amsg written as side-out
      gemm15<3, 3, 256, 1, 4><<<dim3(NA / 64), blk, 0, stream>>>(
          nullptr, 0, S, nullptr, a2b, nullptr, Wo2_b,
          base_b, nullptr, nullptr, douts[d], amsg);
      // S' = inp + (amsg[b2a] - relu(S[b2revb])) @ W_h^T  (gather fused)
      gemm15<2, 2, 256, 0, 4><<<dim3(NB / 64), blk, 0, stream>>>(
          nullptr, 0, amsg, S, b2a, b2revb, Wh_b,
          inp_b, nullptr, pms[d], nullptr, nullptr);
      S = pms[d];
    } else {
      gemm15<3, 3, 256, 0, 4><<<dim3(NA / 64), blk, 0, stream>>>(
          nullptr, 0, S, nullptr, a2b, nullptr, Wo2_b,
          base_b, nullptr, nullptr, douts[d], nullptr);
    }
  }
  mol_mean<<<dim3(4000), blk, 0, stream>>>(dfin, mol);
}